// Round 4
// baseline (283.166 us; speedup 1.0000x reference)
//
#include <hip/hip_runtime.h>
#include <stdint.h>

using bf16x8 = __attribute__((ext_vector_type(8))) short;
using f32x4  = __attribute__((ext_vector_type(4))) float;

__device__ __forceinline__ unsigned short f2bf(float f) {
  union { float f; uint32_t u; } v; v.f = f;
  uint32_t r = v.u + 0x7FFFu + ((v.u >> 16) & 1u);
  return (unsigned short)(r >> 16);
}
__device__ __forceinline__ uint32_t pk2(float a, float b) {
  return (uint32_t)f2bf(a) | ((uint32_t)f2bf(b) << 16);
}
__device__ __forceinline__ f32x4 mfma16(bf16x8 a, bf16x8 b, f32x4 c) {
  return __builtin_amdgcn_mfma_f32_16x16x32_bf16(a, b, c, 0, 0, 0);
}

// ---------------- Kernel 1: per-pixel LayerNorm stats (mu, rstd) ----------------
__global__ __launch_bounds__(256) void k_lnstats(
    const float* __restrict__ xl, const float* __restrict__ xr,
    float* __restrict__ muW, float* __restrict__ rsW)
{
  const int bx = blockIdx.x;
  const int side = bx >> 7, rem = bx & 127;
  const int b = rem >> 1, half = rem & 1;
  const float* x = (side ? xr : xl) + (size_t)b * 131072 + half * 512;
  const int t = threadIdx.x;
  const int px = t * 2;
  float s0=0, s1=0, q0=0, q1=0;
  for (int c = 0; c < 128; ++c) {
    const float2 v = *(const float2*)(x + c*1024 + px);
    s0 += v.x; q0 += v.x*v.x;
    s1 += v.y; q1 += v.y*v.y;
  }
  const int o = (side*64 + b)*1024 + half*512 + px;
  float2 mu, rs;
  mu.x = s0*(1.0f/128.0f); mu.y = s1*(1.0f/128.0f);
  rs.x = rsqrtf(fmaxf(q0*(1.0f/128.0f) - mu.x*mu.x, 0.0f) + 1e-6f);
  rs.y = rsqrtf(fmaxf(q1*(1.0f/128.0f) - mu.y*mu.y, 0.0f) + 1e-6f);
  *(float2*)(muW + o) = mu;
  *(float2*)(rsW + o) = rs;
}

// ---------------- Kernel 1b: weight prep ----------------
__global__ __launch_bounds__(256) void k_wprep(
    const float* __restrict__ lnwl, const float* __restrict__ lnbl,
    const float* __restrict__ lnwr, const float* __restrict__ lnbr,
    const float* __restrict__ Wl1, const float* __restrict__ bl1,
    const float* __restrict__ Wr1, const float* __restrict__ br1,
    const float* __restrict__ Wl2, const float* __restrict__ Wr2,
    unsigned short* __restrict__ Wq, unsigned short* __restrict__ Wv,
    float* __restrict__ bqW)
{
  const int bx = blockIdx.x;
  const int side = bx >> 7, co = bx & 127;
  const float* W1  = side ? Wr1 : Wl1;
  const float* W2  = side ? Wr2 : Wl2;
  const float* b1  = side ? br1 : bl1;
  const float* lnw = side ? lnwr : lnwl;
  const float* lnb = side ? lnbr : lnbl;
  const int t = threadIdx.x;
  const int ci = t >> 1;
  const float lw = lnw[ci], lb = lnb[ci];

  const float* src1 = W1 + (size_t)co*2048 + t*8;
  const float4 a0 = *(const float4*)(src1);
  const float4 a1 = *(const float4*)(src1 + 4);
  float part = (a0.x+a0.y+a0.z+a0.w + a1.x+a1.y+a1.z+a1.w) * lb;
  uint4 pkq;
  pkq.x = pk2(a0.x*lw, a0.y*lw); pkq.y = pk2(a0.z*lw, a0.w*lw);
  pkq.z = pk2(a1.x*lw, a1.y*lw); pkq.w = pk2(a1.z*lw, a1.w*lw);
  *(uint4*)(Wq + (size_t)side*262144 + co*2048 + t*8) = pkq;

  const float* src2 = W2 + (size_t)co*2048 + t*8;
  const float4 c0 = *(const float4*)(src2);
  const float4 c1 = *(const float4*)(src2 + 4);
  uint4 pkv;
  pkv.x = pk2(c0.x, c0.y); pkv.y = pk2(c0.z, c0.w);
  pkv.z = pk2(c1.x, c1.y); pkv.w = pk2(c1.z, c1.w);
  *(uint4*)(Wv + (size_t)side*262144 + co*2048 + t*8) = pkv;

  __shared__ float red[4];
  float v = part;
  v += __shfl_down(v, 32, 64); v += __shfl_down(v, 16, 64);
  v += __shfl_down(v, 8, 64);  v += __shfl_down(v, 4, 64);
  v += __shfl_down(v, 2, 64);  v += __shfl_down(v, 1, 64);
  if ((t & 63) == 0) red[t >> 6] = v;
  __syncthreads();
  if (t == 0) bqW[side*128 + co] = b1[co] + red[0] + red[1] + red[2] + red[3];
}

// ---------------- Kernel 2: conv4x4/s4 as per-image GEMM, double-buffered ----------------
__global__ __launch_bounds__(256) void k_conv(
    const float* __restrict__ xl, const float* __restrict__ xr,
    const unsigned short* __restrict__ Wq, const unsigned short* __restrict__ Wv,
    const float* __restrict__ bqW,
    const float* __restrict__ bl2, const float* __restrict__ br2,
    const float* __restrict__ pos,
    const float* __restrict__ muW, const float* __restrict__ rsW,
    unsigned short* __restrict__ Qbf, unsigned short* __restrict__ Vtbf)
{
  const int bx = blockIdx.x;
  const int ctype = bx >> 6, img = bx & 63;
  const int side = ctype & 1;
  const bool isQ = ctype < 2;
  const float* x = (side ? xr : xl) + (size_t)img * 131072;
  const unsigned short* Bsrc = (isQ ? Wq : Wv) + (size_t)side * 262144;

  const int t = threadIdx.x;
  const int w = t >> 6, l = t & 63, lo = l & 15, g = l >> 4;

  __shared__ __align__(16) unsigned char lds[57344];
  float* muL = (float*)lds;
  float* rsL = (float*)(lds + 4096);

  if (isQ) {
    const int o = (side*64 + img)*1024 + t*4;
    *(float4*)(muL + t*4) = *(const float4*)(muW + o);
    *(float4*)(rsL + t*4) = *(const float4*)(rsW + o);
  }

  const int cl   = t >> 6;
  const int px0  = (t & 63) * 16;
  const int y    = px0 >> 5;
  const int wr   = y & 3;
  const int pbase = (y >> 2)*8 + ((px0 & 31) >> 2);
  const int cout = t >> 1, part = t & 1;

  float4 av[4];
  bf16x8 bv[4];

  auto GLOAD = [&](int kb) {
    const float* xs = x + (size_t)(kb*4 + cl)*1024 + px0;
#pragma unroll
    for (int i = 0; i < 4; ++i) av[i] = *(const float4*)(xs + 4*i);
    const unsigned short* bs = Bsrc + (size_t)cout*2048 + kb*64 + part*32;
#pragma unroll
    for (int i = 0; i < 4; ++i) bv[i] = *(const bf16x8*)(bs + i*8);
  };
  auto SWRITE = [&](int buf) {
    unsigned char* A = lds + 8192  + (buf << 13);
    unsigned char* B = lds + 24576 + (buf << 14);
#pragma unroll
    for (int i = 0; i < 4; ++i) {
      const int p = pbase + i;
      float4 v = av[i];
      if (isQ) {
        const float4 m  = *(const float4*)(muL + px0 + 4*i);
        const float4 rv = *(const float4*)(rsL + px0 + 4*i);
        v.x = (v.x - m.x)*rv.x; v.y = (v.y - m.y)*rv.y;
        v.z = (v.z - m.z)*rv.z; v.w = (v.w - m.w)*rv.w;
      }
      int dst = p*128 + cl*32 + wr*8;
      dst ^= ((p ^ (p >> 3)) & 7) << 4;
      *(uint2*)(A + dst) = make_uint2(pk2(v.x, v.y), pk2(v.z, v.w));
    }
#pragma unroll
    for (int i = 0; i < 4; ++i) {
      const int dst = cout*128 + ((part*64 + i*16) ^ ((cout & 7) << 4));
      *(bf16x8*)(B + dst) = bv[i];
    }
  };

  f32x4 acc[4][2];
#pragma unroll
  for (int a = 0; a < 4; ++a) { acc[a][0] = (f32x4)0.0f; acc[a][1] = (f32x4)0.0f; }

  GLOAD(0);
  if (isQ) __syncthreads();
  SWRITE(0);

  int cur = 0;
  for (int kb = 0; kb < 32; ++kb) {
    __syncthreads();
    if (kb < 31) GLOAD(kb + 1);
    unsigned char* Ac = lds + 8192  + (cur << 13);
    unsigned char* Bc = lds + 24576 + (cur << 14);
    bf16x8 af[4][2], bfr[2][2];
#pragma unroll
    for (int mf = 0; mf < 4; ++mf) {
      const int row = mf*16 + lo;
      const int key = ((row ^ (row >> 3)) & 7) << 4;
#pragma unroll
      for (int kc = 0; kc < 2; ++kc)
        af[mf][kc] = *(const bf16x8*)(Ac + row*128 + ((kc*64 + g*16) ^ key));
    }
#pragma unroll
    for (int nf = 0; nf < 2; ++nf) {
      const int row = w*32 + nf*16 + lo;
      const int key = (row & 7) << 4;
#pragma unroll
      for (int kc = 0; kc < 2; ++kc)
        bfr[nf][kc] = *(const bf16x8*)(Bc + row*128 + ((kc*64 + g*16) ^ key));
    }
    __builtin_amdgcn_s_setprio(1);
#pragma unroll
    for (int kc = 0; kc < 2; ++kc)
#pragma unroll
      for (int nf = 0; nf < 2; ++nf)
#pragma unroll
        for (int mf = 0; mf < 4; ++mf)
          acc[mf][nf] = mfma16(af[mf][kc], bfr[nf][kc], acc[mf][nf]);
    __builtin_amdgcn_s_setprio(0);
    if (kb < 31) SWRITE(cur ^ 1);
    cur ^= 1;
  }

  if (isQ) {
    unsigned short* Qo = Qbf + (size_t)side*524288;
    const float* bq = bqW + side*128;
#pragma unroll
    for (int mf = 0; mf < 4; ++mf)
#pragma unroll
      for (int nf = 0; nf < 2; ++nf) {
        const int co = w*32 + nf*16 + lo;
        const float bb = bq[co];
#pragma unroll
        for (int rr = 0; rr < 4; ++rr) {
          const int pi = mf*16 + g*4 + rr;
          const int p  = img*64 + pi;
          float val = (acc[mf][nf][rr] + bb + pos[co*64 + pi]) * 0.105112052f;
          Qo[(size_t)p*128 + co] = f2bf(val);
        }
      }
  } else {
    unsigned short* Vo = Vtbf + (size_t)side*524288;
    const float* b2 = side ? br2 : bl2;
#pragma unroll
    for (int mf = 0; mf < 4; ++mf)
#pragma unroll
      for (int nf = 0; nf < 2; ++nf) {
        const int co = w*32 + nf*16 + lo;
        const float bb = b2[co];
        const int pi0 = mf*16 + g*4;
        const float v0 = acc[mf][nf][0] + bb + pos[co*64 + pi0];
        const float v1 = acc[mf][nf][1] + bb + pos[co*64 + pi0 + 1];
        const float v2 = acc[mf][nf][2] + bb + pos[co*64 + pi0 + 2];
        const float v3 = acc[mf][nf][3] + bb + pos[co*64 + pi0 + 3];
        *(uint2*)(Vo + (size_t)co*4096 + img*64 + pi0) =
            make_uint2(pk2(v0, v1), pk2(v2, v3));
      }
  }
}

// ---------------- Kernel 3: cross-attention, split-K x4, reg-staged pipeline ----------------
// grid (128 qb, 4 ks, 2 dir). 32 q-rows, 1024 keys/block in 16 tiles of 64.
__global__ __launch_bounds__(256) void k_attn(
    const unsigned short* __restrict__ Qbf,
    const unsigned short* __restrict__ Vtbf,
    float* __restrict__ Opart,   // [2][128][4][32][128] f32
    float* __restrict__ Lpart)   // [2][128][4][32] f32
{
  const int qb = blockIdx.x, ks = blockIdx.y, dir = blockIdx.z;
  const unsigned short* Qp = Qbf  + (size_t)dir*524288;
  const unsigned short* Kp = Qbf  + (size_t)(1-dir)*524288;
  const unsigned short* Vp = Vtbf + (size_t)(1-dir)*524288;

  const int t = threadIdx.x;
  const int w = t >> 6, l = t & 63, lo = l & 15, g = l >> 4;

  __shared__ __align__(16) unsigned char ldsK[16384]; // [64 k][128 c] bf16, swz
  __shared__ __align__(16) unsigned char ldsV[16384]; // [128 c][64 k] bf16, swz
  __shared__ __align__(16) unsigned char ldsP[4096];  // [32 q][64 k] bf16, swz
  __shared__ float lred[4][32];

  bf16x8 aq[2][4];
#pragma unroll
  for (int mf = 0; mf < 2; ++mf)
#pragma unroll
    for (int kc = 0; kc < 4; ++kc)
      aq[mf][kc] = *(const bf16x8*)(Qp + (size_t)(qb*32 + mf*16 + lo)*128 + kc*32 + g*8);

  f32x4 o[2][2];
  o[0][0]=(f32x4)0.0f; o[0][1]=(f32x4)0.0f; o[1][0]=(f32x4)0.0f; o[1][1]=(f32x4)0.0f;
  float ls[2][4] = {{0,0,0,0},{0,0,0,0}};

  uint4 kreg[4], vreg[4];
  const int kt0 = ks * 16;

  auto GLOAD = [&](int kt) {
    const uint4* src = (const uint4*)(Kp + (size_t)kt*8192);
#pragma unroll
    for (int j = 0; j < 4; ++j) {
      const int idx = t + 256*j;
      const int dst = idx*16;
      const int row = dst >> 8;
      kreg[j] = src[(dst ^ ((row & 7) << 4)) >> 4];
    }
#pragma unroll
    for (int j = 0; j < 4; ++j) {
      const int idx = t + 256*j;
      const int c = idx >> 3, i = idx & 7;
      const int inrow = (i*16) ^ ((c & 7) << 4);
      vreg[j] = *(const uint4*)(Vp + (size_t)c*4096 + kt*64 + (inrow >> 1));
    }
  };
  auto SWRITE = [&]() {
#pragma unroll
    for (int j = 0; j < 4; ++j)
      *(uint4*)(ldsK + (t + 256*j)*16) = kreg[j];
#pragma unroll
    for (int j = 0; j < 4; ++j) {
      const int idx = t + 256*j;
      const int c = idx >> 3, i = idx & 7;
      *(uint4*)(ldsV + c*128 + i*16) = vreg[j];
    }
  };

  GLOAD(kt0);
  for (int it = 0; it < 16; ++it) {
    __syncthreads();              // previous tile fully consumed
    SWRITE();                     // regs -> LDS (waits its own vmcnt)
    __syncthreads();              // tile visible
    if (it < 15) GLOAD(kt0 + it + 1);   // issue next loads; hide under compute

    // QK^T
    f32x4 s[2]; s[0] = (f32x4)0.0f; s[1] = (f32x4)0.0f;
    const int krow = w*16 + lo;
    __builtin_amdgcn_s_setprio(1);
#pragma unroll
    for (int kc = 0; kc < 4; ++kc) {
      const bf16x8 bk = *(const bf16x8*)(ldsK + krow*256 + ((kc*64 + g*16) ^ ((krow & 7) << 4)));
      s[0] = mfma16(aq[0][kc], bk, s[0]);
      s[1] = mfma16(aq[1][kc], bk, s[1]);
    }
    __builtin_amdgcn_s_setprio(0);
    // exp (logits are small; no max subtraction), write P, accumulate denom
#pragma unroll
    for (int mf = 0; mf < 2; ++mf)
#pragma unroll
      for (int rr = 0; rr < 4; ++rr) {
        const float e = __expf(s[mf][rr]);
        ls[mf][rr] += e;
        const int q = mf*16 + g*4 + rr;
        const int inrow = (w*32 + lo*2) ^ ((q & 7) << 4);
        *(unsigned short*)(ldsP + q*128 + inrow) = f2bf(e);
      }
    __syncthreads();              // P visible
    // PV
    __builtin_amdgcn_s_setprio(1);
#pragma unroll
    for (int kd = 0; kd < 2; ++kd) {
      bf16x8 pa[2];
#pragma unroll
      for (int mf = 0; mf < 2; ++mf) {
        const int q = mf*16 + lo;
        pa[mf] = *(const bf16x8*)(ldsP + q*128 + ((kd*64 + g*16) ^ ((q & 7) << 4)));
      }
#pragma unroll
      for (int nf = 0; nf < 2; ++nf) {
        const int c = w*32 + nf*16 + lo;
        const bf16x8 bv = *(const bf16x8*)(ldsV + c*128 + ((kd*64 + g*16) ^ ((c & 7) << 4)));
        o[0][nf] = mfma16(pa[0], bv, o[0][nf]);
        o[1][nf] = mfma16(pa[1], bv, o[1][nf]);
      }
    }
    __builtin_amdgcn_s_setprio(0);
  }

  // denominator: reduce over 16 key-lanes, then across waves
#pragma unroll
  for (int mf = 0; mf < 2; ++mf)
#pragma unroll
    for (int rr = 0; rr < 4; ++rr) {
      float v = ls[mf][rr];
      v += __shfl_xor(v, 1, 64);
      v += __shfl_xor(v, 2, 64);
      v += __shfl_xor(v, 4, 64);
      v += __shfl_xor(v, 8, 64);
      ls[mf][rr] = v;
    }
  if (lo == 0) {
#pragma unroll
    for (int mf = 0; mf < 2; ++mf)
#pragma unroll
      for (int rr = 0; rr < 4; ++rr)
        lred[w][mf*16 + g*4 + rr] = ls[mf][rr];
  }
  __syncthreads();

  // write f32 partials
  float* Ob = Opart + (((size_t)dir*128 + qb)*4 + ks)*32*128;
#pragma unroll
  for (int mf = 0; mf < 2; ++mf)
#pragma unroll
    for (int nf = 0; nf < 2; ++nf) {
      const int c = w*32 + nf*16 + lo;
#pragma unroll
      for (int rr = 0; rr < 4; ++rr) {
        const int q = mf*16 + g*4 + rr;
        Ob[q*128 + c] = o[mf][nf][rr];
      }
    }
  if (t < 32)
    Lpart[(((size_t)dir*128 + qb)*4 + ks)*32 + t] =
        lred[0][t] + lred[1][t] + lred[2][t] + lred[3][t];
}

// ---------------- Kernel 3b: combine split-K partials -> F bf16 ----------------
// grid 256: dir*128 + qb. thread: row qr = t>>3, cols (t&7)*16..+15.
__global__ __launch_bounds__(256) void k_reduce(
    const float* __restrict__ Opart, const float* __restrict__ Lpart,
    unsigned short* __restrict__ Fbf)
{
  const int bid = blockIdx.x;
  const int dir = bid >> 7, qb = bid & 127;
  const int t = threadIdx.x;
  const int qr = t >> 3;
  const int cs = (t & 7) * 16;
  const size_t pb = ((size_t)dir*128 + qb)*4;
  float acc[16];
#pragma unroll
  for (int i = 0; i < 16; ++i) acc[i] = 0.f;
  float lsum = 0.f;
#pragma unroll
  for (int s = 0; s < 4; ++s) {
    const float* Ob = Opart + ((pb + s)*32 + qr)*128 + cs;
#pragma unroll
    for (int i = 0; i < 16; i += 4) {
      const float4 v = *(const float4*)(Ob + i);
      acc[i] += v.x; acc[i+1] += v.y; acc[i+2] += v.z; acc[i+3] += v.w;
    }
    lsum += Lpart[(pb + s)*32 + qr];
  }
  const float inv = 1.0f / lsum;
  uint pkw[8];
#pragma unroll
  for (int i = 0; i < 8; ++i) pkw[i] = pk2(acc[2*i]*inv, acc[2*i+1]*inv);
  unsigned short* Fo = Fbf + (size_t)dir*524288 + ((size_t)qb*32 + qr)*128 + cs;
  *(uint4*)(Fo)     = make_uint4(pkw[0], pkw[1], pkw[2], pkw[3]);
  *(uint4*)(Fo + 8) = make_uint4(pkw[4], pkw[5], pkw[6], pkw[7]);
}

// ---------------- Kernel 4: projection + pixel-shuffle + residual ----------------
__global__ __launch_bounds__(256) void k_proj(
    const unsigned short* __restrict__ Fbf,
    const float* __restrict__ Wl3, const float* __restrict__ bl3,
    const float* __restrict__ Wr3, const float* __restrict__ br3,
    const float* __restrict__ beta, const float* __restrict__ gamma,
    const float* __restrict__ xl, const float* __restrict__ xr,
    float* __restrict__ out)
{
  const int nb = blockIdx.x, mb = blockIdx.y, side = blockIdx.z;
  const unsigned short* F = Fbf + (size_t)side*524288;
  const float* W3  = side ? Wr3 : Wl3;
  const float* b3  = side ? br3 : bl3;
  const float* scl = side ? gamma : beta;
  const float* xin = side ? xr : xl;
  float* op = out + (size_t)side*8388608;

  const int t = threadIdx.x;
  const int w = t >> 6, l = t & 63, lo = l & 15, g = l >> 4;

  __shared__ __align__(16) unsigned char Ft[16384];
  __shared__ __align__(16) unsigned char B3[32768];

  {
    const uint4* src = (const uint4*)(F + (size_t)mb*8192);
#pragma unroll
    for (int j = 0; j < 4; ++j) {
      const int idx = t + 256*j;
      const int dst = idx*16;
      const int row = dst >> 8;
      *(uint4*)(Ft + dst) = src[(dst ^ ((row & 7) << 4)) >> 4];
    }
  }
  {
    const int nl = t >> 1, half = t & 1;
    const float* wsrc = W3 + (size_t)(nb*128 + nl)*128 + half*64;
#pragma unroll
    for (int ch = 0; ch < 8; ++ch) {
      const float4 v0 = *(const float4*)(wsrc + ch*8);
      const float4 v1 = *(const float4*)(wsrc + ch*8 + 4);
      uint4 pk;
      pk.x = pk2(v0.x,v0.y); pk.y = pk2(v0.z,v0.w);
      pk.z = pk2(v1.x,v1.y); pk.w = pk2(v1.z,v1.w);
      const int inrow = (half*128 + ch*16) ^ ((nl & 7) << 4);
      *(uint4*)(B3 + nl*256 + inrow) = pk;
    }
  }
  __syncthreads();

  f32x4 acc[4][2];
#pragma unroll
  for (int a=0;a<4;a++) { acc[a][0] = (f32x4)0.0f; acc[a][1] = (f32x4)0.0f; }

  bf16x8 af[4][4];
#pragma unroll
  for (int mf = 0; mf < 4; ++mf) {
    const int row = mf*16 + lo;
#pragma unroll
    for (int kc = 0; kc < 4; ++kc)
      af[mf][kc] = *(const bf16x8*)(Ft + row*256 + ((kc*64 + g*16) ^ ((row & 7) << 4)));
  }
#pragma unroll
  for (int kc = 0; kc < 4; ++kc)
#pragma unroll
    for (int nf = 0; nf < 2; ++nf) {
      const int n = w*32 + nf*16 + lo;
      const bf16x8 bb = *(const bf16x8*)(B3 + n*256 + ((kc*64 + g*16) ^ ((n & 7) << 4)));
#pragma unroll
      for (int mf = 0; mf < 4; ++mf)
        acc[mf][nf] = mfma16(af[mf][kc], bb, acc[mf][nf]);
    }

#pragma unroll
  for (int mf = 0; mf < 4; ++mf)
#pragma unroll
    for (int nf = 0; nf < 2; ++nf) {
      const int n16 = nb*128 + w*32 + nf*16 + lo;
      const int c = n16 >> 4, r4 = (n16 >> 2) & 3, sc = n16 & 3;
      const float scc = scl[c];
      const float bb3 = b3[n16];
#pragma unroll
      for (int rr = 0; rr < 4; ++rr) {
        const int pi = mf*16 + g*4 + rr;
        const int h = pi >> 3, wc = pi & 7;
        const size_t oidx = ((size_t)(mb*128 + c))*1024 + (size_t)(h*4 + r4)*32 + wc*4 + sc;
        op[oidx] = xin[oidx] + scc*(acc[mf][nf][rr] + bb3);
      }
    }
}

extern "C" void kernel_launch(void* const* d_in, const int* in_sizes, int n_in,
                              void* d_out, int out_size, void* d_ws, size_t ws_size,
                              hipStream_t stream) {
  (void)in_sizes; (void)n_in; (void)out_size; (void)ws_size;
  const float* xl   = (const float*)d_in[0];
  const float* xr   = (const float*)d_in[1];
  const float* lnwl = (const float*)d_in[2];
  const float* lnbl = (const float*)d_in[3];
  const float* lnwr = (const float*)d_in[4];
  const float* lnbr = (const float*)d_in[5];
  const float* Wl1  = (const float*)d_in[6];
  const float* bl1  = (const float*)d_in[7];
  const float* Wr1  = (const float*)d_in[8];
  const float* br1  = (const float*)d_in[9];
  const float* Wl2  = (const float*)d_in[10];
  const float* bl2  = (const float*)d_in[11];
  const float* Wr2  = (const float*)d_in[12];
  const float* br2  = (const float*)d_in[13];
  const float* pos  = (const float*)d_in[14];
  const float* beta = (const float*)d_in[15];
  const float* gamma= (const float*)d_in[16];
  const float* Wl3  = (const float*)d_in[17];
  const float* bl3  = (const float*)d_in[18];
  const float* Wr3  = (const float*)d_in[19];
  const float* br3  = (const float*)d_in[20];

  float* muW = (float*)d_ws;                         // [2][64][1024]
  float* rsW = muW + 131072;                         // [2][64][1024]
  float* bqW = rsW + 131072;                         // [2][128]
  unsigned short* Wq   = (unsigned short*)(bqW + 256);  // [2][128][2048]
  unsigned short* Wv   = Wq + 524288;                   // [2][128][2048]
  unsigned short* Qbf  = Wv + 524288;                   // [2][4096][128]
  unsigned short* Vtbf = Qbf + 1048576;                 // [2][128][4096]
  unsigned short* Fbf  = Vtbf + 1048576;                // [2][4096][128]
  float* Opart = (float*)(Fbf + 1048576);               // [2][128][4][32][128]
  float* Lpart = Opart + 4194304;                       // [2][128][4][32]

  k_lnstats<<<256, 256, 0, stream>>>(xl, xr, muW, rsW);
  k_wprep<<<256, 256, 0, stream>>>(lnwl, lnbl, lnwr, lnbr,
      Wl1, bl1, Wr1, br1, Wl2, Wr2, Wq, Wv, bqW);
  k_conv<<<256, 256, 0, stream>>>(xl, xr, Wq, Wv, bqW, bl2, br2, pos,
      muW, rsW, Qbf, Vtbf);
  k_attn<<<dim3(128, 4, 2), 256, 0, stream>>>(Qbf, Vtbf, Opart, Lpart);
  k_reduce<<<256, 256, 0, stream>>>(Opart, Lpart, Fbf);
  k_proj<<<dim3(16, 64, 2), 256, 0, stream>>>(Fbf, Wl3, bl3, Wr3, br3,
      beta, gamma, xl, xr, (float*)d_out);
}

// Round 5
// 157.285 us; speedup vs baseline: 1.8003x; 1.8003x over previous
//
#include <hip/hip_runtime.h>
#include <stdint.h>

using bf16x8 = __attribute__((ext_vector_type(8))) short;
using f32x4  = __attribute__((ext_vector_type(4))) float;

__device__ __forceinline__ unsigned short f2bf(float f) {
  union { float f; uint32_t u; } v; v.f = f;
  uint32_t r = v.u + 0x7FFFu + ((v.u >> 16) & 1u);
  return (unsigned short)(r >> 16);
}
__device__ __forceinline__ uint32_t pk2(float a, float b) {
  return (uint32_t)f2bf(a) | ((uint32_t)f2bf(b) << 16);
}
__device__ __forceinline__ f32x4 mfma16(bf16x8 a, bf16x8 b, f32x4 c) {
  return __builtin_amdgcn_mfma_f32_16x16x32_bf16(a, b, c, 0, 0, 0);
}

// ---------------- Kernel 1: per-pixel LayerNorm stats (mu, rstd) ----------------
__global__ __launch_bounds__(256) void k_lnstats(
    const float* __restrict__ xl, const float* __restrict__ xr,
    float* __restrict__ muW, float* __restrict__ rsW)
{
  const int bx = blockIdx.x;
  const int side = bx >> 7, rem = bx & 127;
  const int b = rem >> 1, half = rem & 1;
  const float* x = (side ? xr : xl) + (size_t)b * 131072 + half * 512;
  const int t = threadIdx.x;
  const int px = t * 2;
  float s0=0, s1=0, q0=0, q1=0;
  for (int c = 0; c < 128; ++c) {
    const float2 v = *(const float2*)(x + c*1024 + px);
    s0 += v.x; q0 += v.x*v.x;
    s1 += v.y; q1 += v.y*v.y;
  }
  const int o = (side*64 + b)*1024 + half*512 + px;
  float2 mu, rs;
  mu.x = s0*(1.0f/128.0f); mu.y = s1*(1.0f/128.0f);
  rs.x = rsqrtf(fmaxf(q0*(1.0f/128.0f) - mu.x*mu.x, 0.0f) + 1e-6f);
  rs.y = rsqrtf(fmaxf(q1*(1.0f/128.0f) - mu.y*mu.y, 0.0f) + 1e-6f);
  *(float2*)(muW + o) = mu;
  *(float2*)(rsW + o) = rs;
}

// ---------------- Kernel 1b: weight prep ----------------
__global__ __launch_bounds__(256) void k_wprep(
    const float* __restrict__ lnwl, const float* __restrict__ lnbl,
    const float* __restrict__ lnwr, const float* __restrict__ lnbr,
    const float* __restrict__ Wl1, const float* __restrict__ bl1,
    const float* __restrict__ Wr1, const float* __restrict__ br1,
    const float* __restrict__ Wl2, const float* __restrict__ Wr2,
    unsigned short* __restrict__ Wq, unsigned short* __restrict__ Wv,
    float* __restrict__ bqW)
{
  const int bx = blockIdx.x;
  const int side = bx >> 7, co = bx & 127;
  const float* W1  = side ? Wr1 : Wl1;
  const float* W2  = side ? Wr2 : Wl2;
  const float* b1  = side ? br1 : bl1;
  const float* lnw = side ? lnwr : lnwl;
  const float* lnb = side ? lnbr : lnbl;
  const int t = threadIdx.x;
  const int ci = t >> 1;
  const float lw = lnw[ci], lb = lnb[ci];

  const float* src1 = W1 + (size_t)co*2048 + t*8;
  const float4 a0 = *(const float4*)(src1);
  const float4 a1 = *(const float4*)(src1 + 4);
  float part = (a0.x+a0.y+a0.z+a0.w + a1.x+a1.y+a1.z+a1.w) * lb;
  uint4 pkq;
  pkq.x = pk2(a0.x*lw, a0.y*lw); pkq.y = pk2(a0.z*lw, a0.w*lw);
  pkq.z = pk2(a1.x*lw, a1.y*lw); pkq.w = pk2(a1.z*lw, a1.w*lw);
  *(uint4*)(Wq + (size_t)side*262144 + co*2048 + t*8) = pkq;

  const float* src2 = W2 + (size_t)co*2048 + t*8;
  const float4 c0 = *(const float4*)(src2);
  const float4 c1 = *(const float4*)(src2 + 4);
  uint4 pkv;
  pkv.x = pk2(c0.x, c0.y); pkv.y = pk2(c0.z, c0.w);
  pkv.z = pk2(c1.x, c1.y); pkv.w = pk2(c1.z, c1.w);
  *(uint4*)(Wv + (size_t)side*262144 + co*2048 + t*8) = pkv;

  __shared__ float red[4];
  float v = part;
  v += __shfl_down(v, 32, 64); v += __shfl_down(v, 16, 64);
  v += __shfl_down(v, 8, 64);  v += __shfl_down(v, 4, 64);
  v += __shfl_down(v, 2, 64);  v += __shfl_down(v, 1, 64);
  if ((t & 63) == 0) red[t >> 6] = v;
  __syncthreads();
  if (t == 0) bqW[side*128 + co] = b1[co] + red[0] + red[1] + red[2] + red[3];
}

// ---------------- Kernel 2: conv4x4/s4 as per-image GEMM, double-buffered ----------------
__global__ __launch_bounds__(256) void k_conv(
    const float* __restrict__ xl, const float* __restrict__ xr,
    const unsigned short* __restrict__ Wq, const unsigned short* __restrict__ Wv,
    const float* __restrict__ bqW,
    const float* __restrict__ bl2, const float* __restrict__ br2,
    const float* __restrict__ pos,
    const float* __restrict__ muW, const float* __restrict__ rsW,
    unsigned short* __restrict__ Qbf, unsigned short* __restrict__ Vtbf)
{
  const int bx = blockIdx.x;
  const int ctype = bx >> 6, img = bx & 63;
  const int side = ctype & 1;
  const bool isQ = ctype < 2;
  const float* x = (side ? xr : xl) + (size_t)img * 131072;
  const unsigned short* Bsrc = (isQ ? Wq : Wv) + (size_t)side * 262144;

  const int t = threadIdx.x;
  const int w = t >> 6, l = t & 63, lo = l & 15, g = l >> 4;

  __shared__ __align__(16) unsigned char lds[57344];
  float* muL = (float*)lds;
  float* rsL = (float*)(lds + 4096);

  if (isQ) {
    const int o = (side*64 + img)*1024 + t*4;
    *(float4*)(muL + t*4) = *(const float4*)(muW + o);
    *(float4*)(rsL + t*4) = *(const float4*)(rsW + o);
  }

  const int cl   = t >> 6;
  const int px0  = (t & 63) * 16;
  const int y    = px0 >> 5;
  const int wr   = y & 3;
  const int pbase = (y >> 2)*8 + ((px0 & 31) >> 2);
  const int cout = t >> 1, part = t & 1;

  float4 av[4];
  bf16x8 bv[4];

  auto GLOAD = [&](int kb) {
    const float* xs = x + (size_t)(kb*4 + cl)*1024 + px0;
#pragma unroll
    for (int i = 0; i < 4; ++i) av[i] = *(const float4*)(xs + 4*i);
    const unsigned short* bs = Bsrc + (size_t)cout*2048 + kb*64 + part*32;
#pragma unroll
    for (int i = 0; i < 4; ++i) bv[i] = *(const bf16x8*)(bs + i*8);
  };
  auto SWRITE = [&](int buf) {
    unsigned char* A = lds + 8192  + (buf << 13);
    unsigned char* B = lds + 24576 + (buf << 14);
#pragma unroll
    for (int i = 0; i < 4; ++i) {
      const int p = pbase + i;
      float4 v = av[i];
      if (isQ) {
        const float4 m  = *(const float4*)(muL + px0 + 4*i);
        const float4 rv = *(const float4*)(rsL + px0 + 4*i);
        v.x = (v.x - m.x)*rv.x; v.y = (v.y - m.y)*rv.y;
        v.z = (v.z - m.z)*rv.z; v.w = (v.w - m.w)*rv.w;
      }
      int dst = p*128 + cl*32 + wr*8;
      dst ^= ((p ^ (p >> 3)) & 7) << 4;
      *(uint2*)(A + dst) = make_uint2(pk2(v.x, v.y), pk2(v.z, v.w));
    }
#pragma unroll
    for (int i = 0; i < 4; ++i) {
      const int dst = cout*128 + ((part*64 + i*16) ^ ((cout & 7) << 4));
      *(bf16x8*)(B + dst) = bv[i];
    }
  };

  f32x4 acc[4][2];
#pragma unroll
  for (int a = 0; a < 4; ++a) { acc[a][0] = (f32x4)0.0f; acc[a][1] = (f32x4)0.0f; }

  GLOAD(0);
  if (isQ) __syncthreads();
  SWRITE(0);

  int cur = 0;
  for (int kb = 0; kb < 32; ++kb) {
    __syncthreads();
    if (kb < 31) GLOAD(kb + 1);
    unsigned char* Ac = lds + 8192  + (cur << 13);
    unsigned char* Bc = lds + 24576 + (cur << 14);
    bf16x8 af[4][2], bfr[2][2];
#pragma unroll
    for (int mf = 0; mf < 4; ++mf) {
      const int row = mf*16 + lo;
      const int key = ((row ^ (row >> 3)) & 7) << 4;
#pragma unroll
      for (int kc = 0; kc < 2; ++kc)
        af[mf][kc] = *(const bf16x8*)(Ac + row*128 + ((kc*64 + g*16) ^ key));
    }
#pragma unroll
    for (int nf = 0; nf < 2; ++nf) {
      const int row = w*32 + nf*16 + lo;
      const int key = (row & 7) << 4;
#pragma unroll
      for (int kc = 0; kc < 2; ++kc)
        bfr[nf][kc] = *(const bf16x8*)(Bc + row*128 + ((kc*64 + g*16) ^ key));
    }
    __builtin_amdgcn_s_setprio(1);
#pragma unroll
    for (int kc = 0; kc < 2; ++kc)
#pragma unroll
      for (int nf = 0; nf < 2; ++nf)
#pragma unroll
        for (int mf = 0; mf < 4; ++mf)
          acc[mf][nf] = mfma16(af[mf][kc], bfr[nf][kc], acc[mf][nf]);
    __builtin_amdgcn_s_setprio(0);
    if (kb < 31) SWRITE(cur ^ 1);
    cur ^= 1;
  }

  if (isQ) {
    unsigned short* Qo = Qbf + (size_t)side*524288;
    const float* bq = bqW + side*128;
#pragma unroll
    for (int mf = 0; mf < 4; ++mf)
#pragma unroll
      for (int nf = 0; nf < 2; ++nf) {
        const int co = w*32 + nf*16 + lo;
        const float bb = bq[co];
#pragma unroll
        for (int rr = 0; rr < 4; ++rr) {
          const int pi = mf*16 + g*4 + rr;
          const int p  = img*64 + pi;
          float val = (acc[mf][nf][rr] + bb + pos[co*64 + pi]) * 0.105112052f;
          Qo[(size_t)p*128 + co] = f2bf(val);
        }
      }
  } else {
    unsigned short* Vo = Vtbf + (size_t)side*524288;
    const float* b2 = side ? br2 : bl2;
#pragma unroll
    for (int mf = 0; mf < 4; ++mf)
#pragma unroll
      for (int nf = 0; nf < 2; ++nf) {
        const int co = w*32 + nf*16 + lo;
        const float bb = b2[co];
        const int pi0 = mf*16 + g*4;
        const float v0 = acc[mf][nf][0] + bb + pos[co*64 + pi0];
        const float v1 = acc[mf][nf][1] + bb + pos[co*64 + pi0 + 1];
        const float v2 = acc[mf][nf][2] + bb + pos[co*64 + pi0 + 2];
        const float v3 = acc[mf][nf][3] + bb + pos[co*64 + pi0 + 3];
        *(uint2*)(Vo + (size_t)co*4096 + img*64 + pi0) =
            make_uint2(pk2(v0, v1), pk2(v2, v3));
      }
  }
}

// ---------------- Kernel 3: cross-attention, split-K x4, direct LDS staging ----------------
// grid (128 qb, 4 ks, 2 dir). 32 q-rows, 1024 keys/block in 16 tiles of 64.
__global__ __launch_bounds__(256) void k_attn(
    const unsigned short* __restrict__ Qbf,
    const unsigned short* __restrict__ Vtbf,
    float* __restrict__ Opart,   // [2][128][4][32][128] f32
    float* __restrict__ Lpart)   // [2][128][4][32] f32
{
  const int qb = blockIdx.x, ks = blockIdx.y, dir = blockIdx.z;
  const unsigned short* Qp = Qbf  + (size_t)dir*524288;
  const unsigned short* Kp = Qbf  + (size_t)(1-dir)*524288;
  const unsigned short* Vp = Vtbf + (size_t)(1-dir)*524288;

  const int t = threadIdx.x;
  const int w = t >> 6, l = t & 63, lo = l & 15, g = l >> 4;

  __shared__ __align__(16) unsigned char ldsK[16384]; // [64 k][128 c] bf16, swz
  __shared__ __align__(16) unsigned char ldsV[16384]; // [128 c][64 k] bf16, swz
  __shared__ __align__(16) unsigned char ldsP[4096];  // [32 q][64 k] bf16, swz
  __shared__ float lred[4][32];

  bf16x8 aq[2][4];
#pragma unroll
  for (int mf = 0; mf < 2; ++mf)
#pragma unroll
    for (int kc = 0; kc < 4; ++kc)
      aq[mf][kc] = *(const bf16x8*)(Qp + (size_t)(qb*32 + mf*16 + lo)*128 + kc*32 + g*8);

  f32x4 o[2][2];
  o[0][0]=(f32x4)0.0f; o[0][1]=(f32x4)0.0f; o[1][0]=(f32x4)0.0f; o[1][1]=(f32x4)0.0f;
  float ls[2][4] = {{0,0,0,0},{0,0,0,0}};

  const int kt0 = ks * 16;
  for (int it = 0; it < 16; ++it) {
    const int kt = kt0 + it;
    __syncthreads();  // previous tile fully consumed (K/V/P free)
    {
      const uint4* src = (const uint4*)(Kp + (size_t)kt*8192);
#pragma unroll
      for (int j = 0; j < 4; ++j) {
        const int idx = t + 256*j;
        const int dst = idx*16;
        const int row = dst >> 8;
        *(uint4*)(ldsK + dst) = src[(dst ^ ((row & 7) << 4)) >> 4];
      }
#pragma unroll
      for (int j = 0; j < 4; ++j) {
        const int idx = t + 256*j;
        const int c = idx >> 3, i = idx & 7;
        const int inrow = (i*16) ^ ((c & 7) << 4);
        const uint4 v = *(const uint4*)(Vp + (size_t)c*4096 + kt*64 + (inrow >> 1));
        *(uint4*)(ldsV + c*128 + i*16) = v;
      }
    }
    __syncthreads();
    // QK^T
    f32x4 s[2]; s[0] = (f32x4)0.0f; s[1] = (f32x4)0.0f;
    const int krow = w*16 + lo;
    __builtin_amdgcn_s_setprio(1);
#pragma unroll
    for (int kc = 0; kc < 4; ++kc) {
      const bf16x8 bk = *(const bf16x8*)(ldsK + krow*256 + ((kc*64 + g*16) ^ ((krow & 7) << 4)));
      s[0] = mfma16(aq[0][kc], bk, s[0]);
      s[1] = mfma16(aq[1][kc], bk, s[1]);
    }
    __builtin_amdgcn_s_setprio(0);
    // exp (no max needed: logits are small), write P, accumulate denom
#pragma unroll
    for (int mf = 0; mf < 2; ++mf)
#pragma unroll
      for (int rr = 0; rr < 4; ++rr) {
        const float e = __expf(s[mf][rr]);
        ls[mf][rr] += e;
        const int q = mf*16 + g*4 + rr;
        const int inrow = (w*32 + lo*2) ^ ((q & 7) << 4);
        *(unsigned short*)(ldsP + q*128 + inrow) = f2bf(e);
      }
    __syncthreads();  // P visible
    // PV
    __builtin_amdgcn_s_setprio(1);
#pragma unroll
    for (int kd = 0; kd < 2; ++kd) {
      bf16x8 pa[2];
#pragma unroll
      for (int mf = 0; mf < 2; ++mf) {
        const int q = mf*16 + lo;
        pa[mf] = *(const bf16x8*)(ldsP + q*128 + ((kd*64 + g*16) ^ ((q & 7) << 4)));
      }
#pragma unroll
      for (int nf = 0; nf < 2; ++nf) {
        const int c = w*32 + nf*16 + lo;
        const bf16x8 bv = *(const bf16x8*)(ldsV + c*128 + ((kd*64 + g*16) ^ ((c & 7) << 4)));
        o[0][nf] = mfma16(pa[0], bv, o[0][nf]);
        o[1][nf] = mfma16(pa[1], bv, o[1][nf]);
      }
    }
    __builtin_amdgcn_s_setprio(0);
  }

  // denominator: reduce over 16 key-lanes, then across waves
#pragma unroll
  for (int mf = 0; mf < 2; ++mf)
#pragma unroll
    for (int rr = 0; rr < 4; ++rr) {
      float v = ls[mf][rr];
      v += __shfl_xor(v, 1, 64);
      v += __shfl_xor(v, 2, 64);
      v += __shfl_xor(v, 4, 64);
      v += __shfl_xor(v, 8, 64);
      ls[mf][rr] = v;
    }
  if (lo == 0) {
#pragma unroll
    for (int mf = 0; mf < 2; ++mf)
#pragma unroll
      for (int rr = 0; rr < 4; ++rr)
        lred[w][mf*16 + g*4 + rr] = ls[mf][rr];
  }
  __syncthreads();

  float* Ob = Opart + (((size_t)dir*128 + qb)*4 + ks)*32*128;
#pragma unroll
  for (int mf = 0; mf < 2; ++mf)
#pragma unroll
    for (int nf = 0; nf < 2; ++nf) {
      const int c = w*32 + nf*16 + lo;
#pragma unroll
      for (int rr = 0; rr < 4; ++rr) {
        const int q = mf*16 + g*4 + rr;
        Ob[q*128 + c] = o[mf][nf][rr];
      }
    }
  if (t < 32)
    Lpart[(((size_t)dir*128 + qb)*4 + ks)*32 + t] =
        lred[0][t] + lred[1][t] + lred[2][t] + lred[3][t];
}

// ---------------- Kernel 3b: combine split-K partials -> F bf16 ----------------
__global__ __launch_bounds__(256) void k_reduce(
    const float* __restrict__ Opart, const float* __restrict__ Lpart,
    unsigned short* __restrict__ Fbf)
{
  const int bid = blockIdx.x;
  const int dir = bid >> 7, qb = bid & 127;
  const int t = threadIdx.x;
  const int qr = t >> 3;
  const int cs = (t & 7) * 16;
  const size_t pb = ((size_t)dir*128 + qb)*4;
  float acc[16];
#pragma unroll
  for (int i = 0; i < 16; ++i) acc[i] = 0.f;
  float lsum = 0.f;
#pragma unroll
  for (int s = 0; s < 4; ++s) {
    const float* Ob = Opart + ((pb + s)*32 + qr)*128 + cs;
#pragma unroll
    for (int i = 0; i < 16; i += 4) {
      const float4 v = *(const float4*)(Ob + i);
      acc[i] += v.x; acc[i+1] += v.y; acc[i+2] += v.z; acc[i+3] += v.w;
    }
    lsum += Lpart[(pb + s)*32 + qr];
  }
  const float inv = 1.0f / lsum;
  uint pkw[8];
#pragma unroll
  for (int i = 0; i < 8; ++i) pkw[i] = pk2(acc[2*i]*inv, acc[2*i+1]*inv);
  unsigned short* Fo = Fbf + (size_t)dir*524288 + ((size_t)qb*32 + qr)*128 + cs;
  *(uint4*)(Fo)     = make_uint4(pkw[0], pkw[1], pkw[2], pkw[3]);
  *(uint4*)(Fo + 8) = make_uint4(pkw[4], pkw[5], pkw[6], pkw[7]);
}

// ---------------- Kernel 4: projection + pixel-shuffle + residual ----------------
__global__ __launch_bounds__(256) void k_proj(
    const unsigned short* __restrict__ Fbf,
    const float* __restrict__ Wl3, const float* __restrict__ bl3,
    const float* __restrict__ Wr3, const float* __restrict__ br3,
    const float* __restrict__ beta, const float* __restrict__ gamma,
    const float* __restrict__ xl, const float* __restrict__ xr,
    float* __restrict__ out)
{
  const int nb = blockIdx.x, mb = blockIdx.y, side = blockIdx.z;
  const unsigned short* F = Fbf + (size_t)side*524288;
  const float* W3  = side ? Wr3 : Wl3;
  const float* b3  = side ? br3 : bl3;
  const float* scl = side ? gamma : beta;
  const float* xin = side ? xr : xl;
  float* op = out + (size_t)side*8388608;

  const int t = threadIdx.x;
  const int w = t >> 6, l = t & 63, lo = l & 15, g = l >> 4;

  __shared__ __align__(16) unsigned char Ft[16384];
  __shared__ __align__(16) unsigned char B3[32768];

  {
    const uint4* src = (const uint4*)(F + (size_t)mb*8192);
#pragma unroll
    for (int j = 0; j < 4; ++j) {
      const int idx = t + 256*j;
      const int dst = idx*16;
      const int row = dst >> 8;
      *(uint4*)(Ft + dst) = src[(dst ^ ((row & 7) << 4)) >> 4];
    }
  }
  {
    const int nl = t >> 1, half = t & 1;
    const float* wsrc = W3 + (size_t)(nb*128 + nl)*128 + half*64;
#pragma unroll
    for (int ch = 0; ch < 8; ++ch) {
      const float4 v0 = *(const float4*)(wsrc + ch*8);
      const float4 v1 = *(const float4*)(wsrc + ch*8 + 4);
      uint4 pk;
      pk.x = pk2(v0.x,v0.y); pk.y = pk2(v0.z,v0.w);
      pk.z = pk2(v1.x,v1.y); pk.w = pk2(v1.z,v1.w);
      const int inrow = (half*128 + ch*16) ^ ((nl & 7) << 4);
      *(uint4*)(B3 + nl*256 + inrow) = pk;
    }
  }
  __syncthreads();

  f32x4 acc[4][2];
#pragma unroll
  for (int a=0;a<4;a++) { acc[a][0] = (f32x4)0.0f; acc[a][1] = (f32x4)0.0f; }

  bf16x8 af[4][4];
#pragma unroll
  for (int mf = 0; mf < 4; ++mf) {
    const int row = mf*16 + lo;
#pragma unroll
    for (int kc = 0; kc < 4; ++kc)
      af[mf][kc] = *(const bf16x8*)(Ft + row*256 + ((kc*64 + g*16) ^ ((row & 7) << 4)));
  }
#pragma unroll
  for (int kc = 0; kc < 4; ++kc)
#pragma unroll
    for (int nf = 0; nf < 2; ++nf) {
      const int n = w*32 + nf*16 + lo;
      const bf16x8 bb = *(const bf16x8*)(B3 + n*256 + ((kc*64 + g*16) ^ ((n & 7) << 4)));
#pragma unroll
      for (int mf = 0; mf < 4; ++mf)
        acc[mf][nf] = mfma16(af[mf][kc], bb, acc[mf][nf]);
    }

#pragma unroll
  for (int mf = 0; mf < 4; ++mf)
#pragma unroll
    for (int nf = 0; nf < 2; ++nf) {
      const int n16 = nb*128 + w*32 + nf*16 + lo;
      const int c = n16 >> 4, r4 = (n16 >> 2) & 3, sc = n16 & 3;
      const float scc = scl[c];
      const float bb3 = b3[n16];
#pragma unroll
      for (int rr = 0; rr < 4; ++rr) {
        const int pi = mf*16 + g*4 + rr;
        const int h = pi >> 3, wc = pi & 7;
        const size_t oidx = ((size_t)(mb*128 + c))*1024 + (size_t)(h*4 + r4)*32 + wc*4 + sc;
        op[oidx] = xin[oidx] + scc*(acc[mf][nf][rr] + bb3);
      }
    }
}

extern "C" void kernel_launch(void* const* d_in, const int* in_sizes, int n_in,
                              void* d_out, int out_size, void* d_ws, size_t ws_size,
                              hipStream_t stream) {
  (void)in_sizes; (void)n_in; (void)out_size; (void)ws_size;
  const float* xl   = (const float*)d_in[0];
  const float* xr   = (const float*)d_in[1];
  const float* lnwl = (const float*)d_in[2];
  const float* lnbl = (const float*)d_in[3];
  const float* lnwr = (const float*)d_in[4];
  const float* lnbr = (const float*)d_in[5];
  const float* Wl1  = (const float*)d_in[6];
  const float* bl1  = (const float*)d_in[7];
  const float* Wr1  = (const float*)d_in[8];
  const float* br1  = (const float*)d_in[9];
  const float* Wl2  = (const float*)d_in[10];
  const float* bl2  = (const float*)d_in[11];
  const float* Wr2  = (const float*)d_in[12];
  const float* br2  = (const float*)d_in[13];
  const float* pos  = (const float*)d_in[14];
  const float* beta = (const float*)d_in[15];
  const float* gamma= (const float*)d_in[16];
  const float* Wl3  = (const float*)d_in[17];
  const float* bl3  = (const float*)d_in[18];
  const float* Wr3  = (const float*)d_in[19];
  const float* br3  = (const float*)d_in[20];

  float* muW = (float*)d_ws;                         // [2][64][1024]
  float* rsW = muW + 131072;                         // [2][64][1024]
  float* bqW = rsW + 131072;                         // [2][128]
  unsigned short* Wq   = (unsigned short*)(bqW + 256);  // [2][128][2048]
  unsigned short* Wv   = Wq + 524288;                   // [2][128][2048]
  unsigned short* Qbf  = Wv + 524288;                   // [2][4096][128]
  unsigned short* Vtbf = Qbf + 1048576;                 // [2][128][4096]
  unsigned short* Fbf  = Vtbf + 1048576;                // [2][4096][128]
  float* Opart = (float*)(Fbf + 1048576);               // [2][128][4][32][128]
  float* Lpart = Opart + 4194304;                       // [2][128][4][32]

  k_lnstats<<<256, 256, 0, stream>>>(xl, xr, muW, rsW);
  k_wprep<<<256, 256, 0, stream>>>(lnwl, lnbl, lnwr, lnbr,
      Wl1, bl1, Wr1, br1, Wl2, Wr2, Wq, Wv, bqW);
  k_conv<<<256, 256, 0, stream>>>(xl, xr, Wq, Wv, bqW, bl2, br2, pos,
      muW, rsW, Qbf, Vtbf);
  k_attn<<<dim3(128, 4, 2), 256, 0, stream>>>(Qbf, Vtbf, Opart, Lpart);
  k_reduce<<<256, 256, 0, stream>>>(Opart, Lpart, Fbf);
  k_proj<<<dim3(16, 64, 2), 256, 0, stream>>>(Fbf, Wl3, bl3, Wr3, br3,
      beta, gamma, xl, xr, (float*)d_out);
}

// Round 6
// 148.770 us; speedup vs baseline: 1.9034x; 1.0572x over previous
//
#include <hip/hip_runtime.h>
#include <stdint.h>

using bf16x8 = __attribute__((ext_vector_type(8))) short;
using f32x4  = __attribute__((ext_vector_type(4))) float;

__device__ __forceinline__ unsigned short f2bf(float f) {
  union { float f; uint32_t u; } v; v.f = f;
  uint32_t r = v.u + 0x7FFFu + ((v.u >> 16) & 1u);
  return (unsigned short)(r >> 16);
}
__device__ __forceinline__ uint32_t pk2(float a, float b) {
  return (uint32_t)f2bf(a) | ((uint32_t)f2bf(b) << 16);
}
__device__ __forceinline__ float bf2f(unsigned short s) {
  union { uint32_t u; float f; } v; v.u = ((uint32_t)s) << 16;
  return v.f;
}
__device__ __forceinline__ f32x4 mfma16(bf16x8 a, bf16x8 b, f32x4 c) {
  return __builtin_amdgcn_mfma_f32_16x16x32_bf16(a, b, c, 0, 0, 0);
}

// ---------------- Kernel 1: per-pixel LayerNorm stats (mu, rstd) ----------------
__global__ __launch_bounds__(256) void k_lnstats(
    const float* __restrict__ xl, const float* __restrict__ xr,
    float* __restrict__ muW, float* __restrict__ rsW)
{
  const int bx = blockIdx.x;
  const int side = bx >> 7, rem = bx & 127;
  const int b = rem >> 1, half = rem & 1;
  const float* x = (side ? xr : xl) + (size_t)b * 131072 + half * 512;
  const int t = threadIdx.x;
  const int px = t * 2;
  float s0=0, s1=0, q0=0, q1=0;
#pragma unroll 4
  for (int c = 0; c < 128; ++c) {
    const float2 v = *(const float2*)(x + c*1024 + px);
    s0 += v.x; q0 += v.x*v.x;
    s1 += v.y; q1 += v.y*v.y;
  }
  const int o = (side*64 + b)*1024 + half*512 + px;
  float2 mu, rs;
  mu.x = s0*(1.0f/128.0f); mu.y = s1*(1.0f/128.0f);
  rs.x = rsqrtf(fmaxf(q0*(1.0f/128.0f) - mu.x*mu.x, 0.0f) + 1e-6f);
  rs.y = rsqrtf(fmaxf(q1*(1.0f/128.0f) - mu.y*mu.y, 0.0f) + 1e-6f);
  *(float2*)(muW + o) = mu;
  *(float2*)(rsW + o) = rs;
}

// ---------------- Kernel 1b: weight prep ----------------
// Wq/Wv emitted in K-tiled layout: [side][kb=32][cout=128][64 k] bf16.
__global__ __launch_bounds__(256) void k_wprep(
    const float* __restrict__ lnwl, const float* __restrict__ lnbl,
    const float* __restrict__ lnwr, const float* __restrict__ lnbr,
    const float* __restrict__ Wl1, const float* __restrict__ bl1,
    const float* __restrict__ Wr1, const float* __restrict__ br1,
    const float* __restrict__ Wl2, const float* __restrict__ Wr2,
    unsigned short* __restrict__ Wq, unsigned short* __restrict__ Wv,
    float* __restrict__ bqW)
{
  const int bx = blockIdx.x;
  const int side = bx >> 7, co = bx & 127;
  const float* W1  = side ? Wr1 : Wl1;
  const float* W2  = side ? Wr2 : Wl2;
  const float* b1  = side ? br1 : bl1;
  const float* lnw = side ? lnwr : lnwl;
  const float* lnb = side ? lnbr : lnbl;
  const int t = threadIdx.x;
  const int ci = t >> 1;
  const float lw = lnw[ci], lb = lnb[ci];

  const size_t dsto = (size_t)(side*32 + (t>>3))*8192 + (size_t)co*64 + (t&7)*8;

  const float* src1 = W1 + (size_t)co*2048 + t*8;
  const float4 a0 = *(const float4*)(src1);
  const float4 a1 = *(const float4*)(src1 + 4);
  float part = (a0.x+a0.y+a0.z+a0.w + a1.x+a1.y+a1.z+a1.w) * lb;
  uint4 pkq;
  pkq.x = pk2(a0.x*lw, a0.y*lw); pkq.y = pk2(a0.z*lw, a0.w*lw);
  pkq.z = pk2(a1.x*lw, a1.y*lw); pkq.w = pk2(a1.z*lw, a1.w*lw);
  *(uint4*)(Wq + dsto) = pkq;

  const float* src2 = W2 + (size_t)co*2048 + t*8;
  const float4 c0 = *(const float4*)(src2);
  const float4 c1 = *(const float4*)(src2 + 4);
  uint4 pkv;
  pkv.x = pk2(c0.x, c0.y); pkv.y = pk2(c0.z, c0.w);
  pkv.z = pk2(c1.x, c1.y); pkv.w = pk2(c1.z, c1.w);
  *(uint4*)(Wv + dsto) = pkv;

  __shared__ float red[4];
  float v = part;
  v += __shfl_down(v, 32, 64); v += __shfl_down(v, 16, 64);
  v += __shfl_down(v, 8, 64);  v += __shfl_down(v, 4, 64);
  v += __shfl_down(v, 2, 64);  v += __shfl_down(v, 1, 64);
  if ((t & 63) == 0) red[t >> 6] = v;
  __syncthreads();
  if (t == 0) bqW[side*128 + co] = b1[co] + red[0] + red[1] + red[2] + red[3];
}

// ---------------- Kernel 2: conv GEMM, split-K x4, direct staging ----------------
// grid 1024: bid = (ctype*64+img)*4 + ks. M=64, N=128, K=512 per block (8 x BK=64).
// Emits bf16 partials Cpart[bid][c=128][p=64] (no bias).
__global__ __launch_bounds__(256) void k_conv(
    const float* __restrict__ xl, const float* __restrict__ xr,
    const unsigned short* __restrict__ Wq, const unsigned short* __restrict__ Wv,
    const float* __restrict__ muW, const float* __restrict__ rsW,
    unsigned short* __restrict__ Cpart)
{
  const int bid = blockIdx.x;
  const int ks = bid & 3;
  const int img = (bid >> 2) & 63;
  const int ctype = bid >> 8;
  const int side = ctype & 1;
  const bool isQ = ctype < 2;
  const float* x = (side ? xr : xl) + (size_t)img * 131072;
  const unsigned short* Bsrc = (isQ ? Wq : Wv) + (size_t)side * 262144;

  const int t = threadIdx.x;
  const int w = t >> 6, l = t & 63, lo = l & 15, g = l >> 4;

  __shared__ __align__(16) unsigned char lds[24576];  // [0,8K) A, [8K,24K) B
  unsigned char* A = lds;
  unsigned char* B = lds + 8192;

  // A staging geometry (loop-invariant)
  const int cl   = t >> 6;                 // channel within 4-chunk
  const int px0  = (t & 63) * 16;          // 16 consecutive pixels (one row span)
  const int y    = px0 >> 5;
  const int wr   = y & 3;                  // ky
  const int pbase = (y >> 2)*8 + ((px0 & 31) >> 2);

  // mu/rs for this thread's 16 pixels -> registers (loop-invariant)
  float4 mu4[4], rs4[4];
  if (isQ) {
    const int o = (side*64 + img)*1024 + px0;
#pragma unroll
    for (int i = 0; i < 4; ++i) {
      mu4[i] = *(const float4*)(muW + o + 4*i);
      rs4[i] = *(const float4*)(rsW + o + 4*i);
    }
  }

  const int cout = t >> 1, part = t & 1;   // B staging geometry
  const int keyB = ((cout ^ (cout >> 3)) & 7) << 4;

  f32x4 acc[4][2];
#pragma unroll
  for (int a = 0; a < 4; ++a) { acc[a][0] = (f32x4)0.0f; acc[a][1] = (f32x4)0.0f; }

  for (int it = 0; it < 8; ++it) {
    const int kb = ks*8 + it;
    __syncthreads();   // previous tile consumed
    // ---- A stage: 4 float4 x-loads, LN (Q), pack to bf16, swizzled LDS ----
    {
      const float* xs = x + (size_t)(kb*4 + cl)*1024 + px0;
#pragma unroll
      for (int i = 0; i < 4; ++i) {
        float4 v = *(const float4*)(xs + 4*i);
        if (isQ) {
          v.x = (v.x - mu4[i].x)*rs4[i].x; v.y = (v.y - mu4[i].y)*rs4[i].y;
          v.z = (v.z - mu4[i].z)*rs4[i].z; v.w = (v.w - mu4[i].w)*rs4[i].w;
        }
        const int p = pbase + i;
        int dst = p*128 + cl*32 + wr*8;
        dst ^= ((p ^ (p >> 3)) & 7) << 4;
        *(uint2*)(A + dst) = make_uint2(pk2(v.x, v.y), pk2(v.z, v.w));
      }
    }
    // ---- B stage: contiguous 64B/thread from K-tiled weights ----
    {
      const unsigned short* bs = Bsrc + (size_t)kb*8192 + t*32;
#pragma unroll
      for (int i = 0; i < 4; ++i) {
        const bf16x8 v = *(const bf16x8*)(bs + i*8);
        *(bf16x8*)(B + cout*128 + ((part*64 + i*16) ^ keyB)) = v;
      }
    }
    __syncthreads();
    // ---- fragments + MFMA ----
    bf16x8 af[4][2], bfr[2][2];
#pragma unroll
    for (int mf = 0; mf < 4; ++mf) {
      const int row = mf*16 + lo;
      const int key = ((row ^ (row >> 3)) & 7) << 4;
#pragma unroll
      for (int kc = 0; kc < 2; ++kc)
        af[mf][kc] = *(const bf16x8*)(A + row*128 + ((kc*64 + g*16) ^ key));
    }
#pragma unroll
    for (int nf = 0; nf < 2; ++nf) {
      const int row = w*32 + nf*16 + lo;
      const int key = ((row ^ (row >> 3)) & 7) << 4;
#pragma unroll
      for (int kc = 0; kc < 2; ++kc)
        bfr[nf][kc] = *(const bf16x8*)(B + row*128 + ((kc*64 + g*16) ^ key));
    }
    __builtin_amdgcn_s_setprio(1);
#pragma unroll
    for (int kc = 0; kc < 2; ++kc)
#pragma unroll
      for (int nf = 0; nf < 2; ++nf)
#pragma unroll
        for (int mf = 0; mf < 4; ++mf)
          acc[mf][nf] = mfma16(af[mf][kc], bfr[nf][kc], acc[mf][nf]);
    __builtin_amdgcn_s_setprio(0);
  }

  // ---- epilogue: bf16 partials, [c][p] layout ----
  unsigned short* Cp = Cpart + (size_t)bid * 8192;
#pragma unroll
  for (int mf = 0; mf < 4; ++mf)
#pragma unroll
    for (int nf = 0; nf < 2; ++nf) {
      const int c = w*32 + nf*16 + lo;
      const int p0 = mf*16 + g*4;
      *(uint2*)(Cp + c*64 + p0) =
          make_uint2(pk2(acc[mf][nf][0], acc[mf][nf][1]),
                     pk2(acc[mf][nf][2], acc[mf][nf][3]));
    }
}

// ---------------- Kernel 2b: combine conv split-K partials ----------------
// grid 256: bid2 = ctype*64+img. Adds bias+pos, Q-scale; writes Qbf / transposed Vtbf.
__global__ __launch_bounds__(256) void k_convred(
    const unsigned short* __restrict__ Cpart,
    const float* __restrict__ bqW,
    const float* __restrict__ bl2, const float* __restrict__ br2,
    const float* __restrict__ pos,
    unsigned short* __restrict__ Qbf, unsigned short* __restrict__ Vtbf)
{
  const int bid2 = blockIdx.x;
  const int ctype = bid2 >> 6, img = bid2 & 63;
  const int side = ctype & 1;
  const bool isQ = ctype < 2;
  const int t = threadIdx.x;

  __shared__ float S[64][130];   // [p][c], pad 130 for bank spread

  const int c = t >> 1, p0 = (t & 1) * 32;
  {
    float acc[32];
#pragma unroll
    for (int j = 0; j < 32; ++j) acc[j] = 0.f;
#pragma unroll
    for (int s = 0; s < 4; ++s) {
      const unsigned short* Cp = Cpart + ((size_t)(bid2*4 + s))*8192 + c*64 + p0;
#pragma unroll
      for (int j8 = 0; j8 < 4; ++j8) {
        const bf16x8 v = *(const bf16x8*)(Cp + j8*8);
#pragma unroll
        for (int e = 0; e < 8; ++e)
          acc[j8*8 + e] += bf2f((unsigned short)v[e]);
      }
    }
#pragma unroll
    for (int j = 0; j < 32; ++j) S[p0 + j][c] = acc[j];
  }
  __syncthreads();

  if (isQ) {
    const float* bq = bqW + side*128;
    const int p = t >> 2, c0 = (t & 3) * 32;
    const int rot = (t & 3) * 4;     // pair-rotation to avoid 4-way bank conflict
    uint32_t pk[16];
#pragma unroll
    for (int j2 = 0; j2 < 16; ++j2) {
      const int jj = (j2 + rot) & 15;
      const int ca = c0 + jj*2;
      const float2 sv = *(const float2*)(&S[p][ca]);
      const float va = (sv.x + bq[ca]     + pos[ca*64 + p])     * 0.105112052f;
      const float vb = (sv.y + bq[ca + 1] + pos[(ca+1)*64 + p]) * 0.105112052f;
      pk[jj] = pk2(va, vb);
    }
    unsigned short* Qo = Qbf + (size_t)side*524288 + ((size_t)(img*64 + p))*128 + c0;
    *(uint4*)(Qo)      = make_uint4(pk[0],  pk[1],  pk[2],  pk[3]);
    *(uint4*)(Qo + 8)  = make_uint4(pk[4],  pk[5],  pk[6],  pk[7]);
    *(uint4*)(Qo + 16) = make_uint4(pk[8],  pk[9],  pk[10], pk[11]);
    *(uint4*)(Qo + 24) = make_uint4(pk[12], pk[13], pk[14], pk[15]);
  } else {
    const float* b2 = side ? br2 : bl2;
    const float bb = b2[c];
    uint32_t pk[16];
#pragma unroll
    for (int j2 = 0; j2 < 16; ++j2) {
      const int pa = p0 + j2*2;
      const float va = S[pa][c]     + bb + pos[c*64 + pa];
      const float vb = S[pa + 1][c] + bb + pos[c*64 + pa + 1];
      pk[j2] = pk2(va, vb);
    }
    unsigned short* Vo = Vtbf + (size_t)side*524288 + (size_t)c*4096 + img*64 + p0;
    *(uint4*)(Vo)      = make_uint4(pk[0],  pk[1],  pk[2],  pk[3]);
    *(uint4*)(Vo + 8)  = make_uint4(pk[4],  pk[5],  pk[6],  pk[7]);
    *(uint4*)(Vo + 16) = make_uint4(pk[8],  pk[9],  pk[10], pk[11]);
    *(uint4*)(Vo + 24) = make_uint4(pk[12], pk[13], pk[14], pk[15]);
  }
}

// ---------------- Kernel 3: cross-attention, split-K x4, direct LDS staging ----------------
__global__ __launch_bounds__(256) void k_attn(
    const unsigned short* __restrict__ Qbf,
    const unsigned short* __restrict__ Vtbf,
    float* __restrict__ Opart,   // [2][128][4][32][128] f32
    float* __restrict__ Lpart)   // [2][128][4][32] f32
{
  const int qb = blockIdx.x, ks = blockIdx.y, dir = blockIdx.z;
  const unsigned short* Qp = Qbf  + (size_t)dir*524288;
  const unsigned short* Kp = Qbf  + (size_t)(1-dir)*524288;
  const unsigned short* Vp = Vtbf + (size_t)(1-dir)*524288;

  const int t = threadIdx.x;
  const int w = t >> 6, l = t & 63, lo = l & 15, g = l >> 4;

  __shared__ __align__(16) unsigned char ldsK[16384];
  __shared__ __align__(16) unsigned char ldsV[16384];
  __shared__ __align__(16) unsigned char ldsP[4096];
  __shared__ float lred[4][32];

  bf16x8 aq[2][4];
#pragma unroll
  for (int mf = 0; mf < 2; ++mf)
#pragma unroll
    for (int kc = 0; kc < 4; ++kc)
      aq[mf][kc] = *(const bf16x8*)(Qp + (size_t)(qb*32 + mf*16 + lo)*128 + kc*32 + g*8);

  f32x4 o[2][2];
  o[0][0]=(f32x4)0.0f; o[0][1]=(f32x4)0.0f; o[1][0]=(f32x4)0.0f; o[1][1]=(f32x4)0.0f;
  float ls[2][4] = {{0,0,0,0},{0,0,0,0}};

  const int kt0 = ks * 16;
  for (int it = 0; it < 16; ++it) {
    const int kt = kt0 + it;
    __syncthreads();
    {
      const uint4* src = (const uint4*)(Kp + (size_t)kt*8192);
#pragma unroll
      for (int j = 0; j < 4; ++j) {
        const int idx = t + 256*j;
        const int dst = idx*16;
        const int row = dst >> 8;
        *(uint4*)(ldsK + dst) = src[(dst ^ ((row & 7) << 4)) >> 4];
      }
#pragma unroll
      for (int j = 0; j < 4; ++j) {
        const int idx = t + 256*j;
        const int c = idx >> 3, i = idx & 7;
        const int inrow = (i*16) ^ ((c & 7) << 4);
        const uint4 v = *(const uint4*)(Vp + (size_t)c*4096 + kt*64 + (inrow >> 1));
        *(uint4*)(ldsV + c*128 + i*16) = v;
      }
    }
    __syncthreads();
    f32x4 s[2]; s[0] = (f32x4)0.0f; s[1] = (f32x4)0.0f;
    const int krow = w*16 + lo;
    __builtin_amdgcn_s_setprio(1);
#pragma unroll
    for (int kc = 0; kc < 4; ++kc) {
      const bf16x8 bk = *(const bf16x8*)(ldsK + krow*256 + ((kc*64 + g*16) ^ ((krow & 7) << 4)));
      s[0] = mfma16(aq[0][kc], bk, s[0]);
      s[1] = mfma16(aq[1][kc], bk, s[1]);
    }
    __builtin_amdgcn_s_setprio(0);
#pragma unroll
    for (int mf = 0; mf < 2; ++mf)
#pragma unroll
      for (int rr = 0; rr < 4; ++rr) {
        const float e = __expf(s[mf][rr]);
        ls[mf][rr] += e;
        const int q = mf*16 + g*4 + rr;
        const int inrow = (w*32 + lo*2) ^ ((q & 7) << 4);
        *(unsigned short*)(ldsP + q*128 + inrow) = f2bf(e);
      }
    __syncthreads();
    __builtin_amdgcn_s_setprio(1);
#pragma unroll
    for (int kd = 0; kd < 2; ++kd) {
      bf16x8 pa[2];
#pragma unroll
      for (int mf = 0; mf < 2; ++mf) {
        const int q = mf*16 + lo;
        pa[mf] = *(const bf16x8*)(ldsP + q*128 + ((kd*64 + g*16) ^ ((q & 7) << 4)));
      }
#pragma unroll
      for (int nf = 0; nf < 2; ++nf) {
        const int c = w*32 + nf*16 + lo;
        const bf16x8 bv = *(const bf16x8*)(ldsV + c*128 + ((kd*64 + g*16) ^ ((c & 7) << 4)));
        o[0][nf] = mfma16(pa[0], bv, o[0][nf]);
        o[1][nf] = mfma16(pa[1], bv, o[1][nf]);
      }
    }
    __builtin_amdgcn_s_setprio(0);
  }

#pragma unroll
  for (int mf = 0; mf < 2; ++mf)
#pragma unroll
    for (int rr = 0; rr < 4; ++rr) {
      float v = ls[mf][rr];
      v += __shfl_xor(v, 1, 64);
      v += __shfl_xor(v, 2, 64);
      v += __shfl_xor(v, 4, 64);
      v += __shfl_xor(v, 8, 64);
      ls[mf][rr] = v;
    }
  if (lo == 0) {
#pragma unroll
    for (int mf = 0; mf < 2; ++mf)
#pragma unroll
      for (int rr = 0; rr < 4; ++rr)
        lred[w][mf*16 + g*4 + rr] = ls[mf][rr];
  }
  __syncthreads();

  float* Ob = Opart + (((size_t)dir*128 + qb)*4 + ks)*32*128;
#pragma unroll
  for (int mf = 0; mf < 2; ++mf)
#pragma unroll
    for (int nf = 0; nf < 2; ++nf) {
      const int c = w*32 + nf*16 + lo;
#pragma unroll
      for (int rr = 0; rr < 4; ++rr) {
        const int q = mf*16 + g*4 + rr;
        Ob[q*128 + c] = o[mf][nf][rr];
      }
    }
  if (t < 32)
    Lpart[(((size_t)dir*128 + qb)*4 + ks)*32 + t] =
        lred[0][t] + lred[1][t] + lred[2][t] + lred[3][t];
}

// ---------------- Kernel 3b: combine split-K partials -> F bf16 ----------------
__global__ __launch_bounds__(256) void k_reduce(
    const float* __restrict__ Opart, const float* __restrict__ Lpart,
    unsigned short* __restrict__ Fbf)
{
  const int bid = blockIdx.x;
  const int dir = bid >> 7, qb = bid & 127;
  const int t = threadIdx.x;
  const int qr = t >> 3;
  const int cs = (t & 7) * 16;
  const size_t pb = ((size_t)dir*128 + qb)*4;
  float acc[16];
#pragma unroll
  for (int i = 0; i < 16; ++i) acc[i] = 0.f;
  float lsum = 0.f;
#pragma unroll
  for (int s = 0; s < 4; ++s) {
    const float* Ob = Opart + ((pb + s)*32 + qr)*128 + cs;
#pragma unroll
    for (int i = 0; i < 16; i += 4) {
      const float4 v = *(const float4*)(Ob + i);
      acc[i] += v.x; acc[i+1] += v.y; acc[i+2] += v.z; acc[i+3] += v.w;
    }
    lsum += Lpart[(pb + s)*32 + qr];
  }
  const float inv = 1.0f / lsum;
  uint32_t pkw[8];
#pragma unroll
  for (int i = 0; i < 8; ++i) pkw[i] = pk2(acc[2*i]*inv, acc[2*i+1]*inv);
  unsigned short* Fo = Fbf + (size_t)dir*524288 + ((size_t)qb*32 + qr)*128 + cs;
  *(uint4*)(Fo)     = make_uint4(pkw[0], pkw[1], pkw[2], pkw[3]);
  *(uint4*)(Fo + 8) = make_uint4(pkw[4], pkw[5], pkw[6], pkw[7]);
}

// ---------------- Kernel 4: projection + pixel-shuffle + residual ----------------
__global__ __launch_bounds__(256) void k_proj(
    const unsigned short* __restrict__ Fbf,
    const float* __restrict__ Wl3, const float* __restrict__ bl3,
    const float* __restrict__ Wr3, const float* __restrict__ br3,
    const float* __restrict__ beta, const float* __restrict__ gamma,
    const float* __restrict__ xl, const float* __restrict__ xr,
    float* __restrict__ out)
{
  const int nb = blockIdx.x, mb = blockIdx.y, side = blockIdx.z;
  const unsigned short* F = Fbf + (size_t)side*524288;
  const float* W3  = side ? Wr3 : Wl3;
  const float* b3  = side ? br3 : bl3;
  const float* scl = side ? gamma : beta;
  const float* xin = side ? xr : xl;
  float* op = out + (size_t)side*8388608;

  const int t = threadIdx.x;
  const int w = t >> 6, l = t & 63, lo = l & 15, g = l >> 4;

  __shared__ __align__(16) unsigned char Ft[16384];
  __shared__ __align__(16) unsigned char B3[32768];

  {
    const uint4* src = (const uint4*)(F + (size_t)mb*8192);
#pragma unroll
    for (int j = 0; j < 4; ++j) {
      const int idx = t + 256*j;
      const int dst = idx*16;
      const int row = dst >> 8;
      *(uint4*)(Ft + dst) = src[(dst ^ ((row & 7) << 4)) >> 4];
    }
  }
  {
    const int nl = t >> 1, half = t & 1;
    const float* wsrc = W3 + (size_t)(nb*128 + nl)*128 + half*64;
#pragma unroll
    for (int ch = 0; ch < 8; ++ch) {
      const float4 v0 = *(const float4*)(wsrc + ch*8);
      const float4 v1 = *(const float4*)(wsrc + ch*8 + 4);
      uint4 pk;
      pk.x = pk2(v0.x,v0.y); pk.y = pk2(v0.z,v0.w);
      pk.z = pk2(v1.x,v1.y); pk.w = pk2(v1.z,v1.w);
      const int inrow = (half*128 + ch*16) ^ ((nl & 7) << 4);
      *(uint4*)(B3 + nl*256 + inrow) = pk;
    }
  }
  __syncthreads();

  f32x4 acc[4][2];
#pragma unroll
  for (int a=0;a<4;a++) { acc[a][0] = (f32x4)0.0f; acc[a][1] = (f32x4)0.0f; }

  bf16x8 af[4][4];
#pragma unroll
  for (int mf = 0; mf < 4; ++mf) {
    const int row = mf*16 + lo;
#pragma unroll
    for (int kc = 0; kc < 4; ++kc)
      af[mf][kc] = *(const bf16x8*)(Ft + row*256 + ((kc*64 + g*16) ^ ((row & 7) << 4)));
  }
#pragma unroll
  for (int kc = 0; kc < 4; ++kc)
#pragma unroll
    for (int nf = 0; nf < 2; ++nf) {
      const int n = w*32 + nf*16 + lo;
      const bf16x8 bb = *(const bf16x8*)(B3 + n*256 + ((kc*64 + g*16) ^ ((n & 7) << 4)));
#pragma unroll
      for (int mf = 0; mf < 4; ++mf)
        acc[mf][nf] = mfma16(af[mf][kc], bb, acc[mf][nf]);
    }

#pragma unroll
  for (int mf = 0; mf < 4; ++mf)
#pragma unroll
    for (int nf = 0; nf < 2; ++nf) {
      const int n16 = nb*128 + w*32 + nf*16 + lo;
      const int c = n16 >> 4, r4 = (n16 >> 2) & 3, sc = n16 & 3;
      const float scc = scl[c];
      const float bb3 = b3[n16];
#pragma unroll
      for (int rr = 0; rr < 4; ++rr) {
        const int pi = mf*16 + g*4 + rr;
        const int h = pi >> 3, wc = pi & 7;
        const size_t oidx = ((size_t)(mb*128 + c))*1024 + (size_t)(h*4 + r4)*32 + wc*4 + sc;
        op[oidx] = xin[oidx] + scc*(acc[mf][nf][rr] + bb3);
      }
    }
}

extern "C" void kernel_launch(void* const* d_in, const int* in_sizes, int n_in,
                              void* d_out, int out_size, void* d_ws, size_t ws_size,
                              hipStream_t stream) {
  (void)in_sizes; (void)n_in; (void)out_size; (void)ws_size;
  const float* xl   = (const float*)d_in[0];
  const float* xr   = (const float*)d_in[1];
  const float* lnwl = (const float*)d_in[2];
  const float* lnbl = (const float*)d_in[3];
  const float* lnwr = (const float*)d_in[4];
  const float* lnbr = (const float*)d_in[5];
  const float* Wl1  = (const float*)d_in[6];
  const float* bl1  = (const float*)d_in[7];
  const float* Wr1  = (const float*)d_in[8];
  const float* br1  = (const float*)d_in[9];
  const float* Wl2  = (const float*)d_in[10];
  const float* bl2  = (const float*)d_in[11];
  const float* Wr2  = (const float*)d_in[12];
  const float* br2  = (const float*)d_in[13];
  const float* pos  = (const float*)d_in[14];
  const float* beta = (const float*)d_in[15];
  const float* gamma= (const float*)d_in[16];
  const float* Wl3  = (const float*)d_in[17];
  const float* bl3  = (const float*)d_in[18];
  const float* Wr3  = (const float*)d_in[19];
  const float* br3  = (const float*)d_in[20];

  float* muW = (float*)d_ws;                            // [2][64][1024]
  float* rsW = muW + 131072;                            // [2][64][1024]
  float* bqW = rsW + 131072;                            // [2][128]
  unsigned short* Wq   = (unsigned short*)(bqW + 256);  // [2][32][128][64]
  unsigned short* Wv   = Wq + 524288;                   // [2][32][128][64]
  unsigned short* Qbf  = Wv + 524288;                   // [2][4096][128]
  unsigned short* Vtbf = Qbf + 1048576;                 // [2][128][4096]
  unsigned short* Fbf  = Vtbf + 1048576;                // [2][4096][128]
  unsigned short* Cpart = Fbf + 1048576;                // [1024][128][64] bf16 (16.8MB)
  float* Opart = (float*)Cpart;                         // alias: [2][128][4][32][128] f32
  float* Lpart = (float*)(Cpart + 8388608);             // [2][128][4][32] f32

  k_lnstats<<<256, 256, 0, stream>>>(xl, xr, muW, rsW);
  k_wprep<<<256, 256, 0, stream>>>(lnwl, lnbl, lnwr, lnbr,
      Wl1, bl1, Wr1, br1, Wl2, Wr2, Wq, Wv, bqW);
  k_conv<<<1024, 256, 0, stream>>>(xl, xr, Wq, Wv, muW, rsW, Cpart);
  k_convred<<<256, 256, 0, stream>>>(Cpart, bqW, bl2, br2, pos, Qbf, Vtbf);
  k_attn<<<dim3(128, 4, 2), 256, 0, stream>>>(Qbf, Vtbf, Opart, Lpart);
  k_reduce<<<256, 256, 0, stream>>>(Opart, Lpart, Fbf);
  k_proj<<<dim3(16, 64, 2), 256, 0, stream>>>(Fbf, Wl3, bl3, Wr3, br3,
      beta, gamma, xl, xr, (float*)d_out);
}

// Round 7
// 135.767 us; speedup vs baseline: 2.0857x; 1.0958x over previous
//
#include <hip/hip_runtime.h>
#include <stdint.h>

using bf16x8 = __attribute__((ext_vector_type(8))) short;
using f32x4  = __attribute__((ext_vector_type(4))) float;

__device__ __forceinline__ unsigned short f2bf(float f) {
  union { float f; uint32_t u; } v; v.f = f;
  uint32_t r = v.u + 0x7FFFu + ((v.u >> 16) & 1u);
  return (unsigned short)(r >> 16);
}
__device__ __forceinline__ uint32_t pk2(float a, float b) {
  return (uint32_t)f2bf(a) | ((uint32_t)f2bf(b) << 16);
}
__device__ __forceinline__ float bf2f(unsigned short s) {
  union { uint32_t u; float f; } v; v.u = ((uint32_t)s) << 16;
  return v.f;
}
__device__ __forceinline__ f32x4 mfma16(bf16x8 a, bf16x8 b, f32x4 c) {
  return __builtin_amdgcn_mfma_f32_16x16x32_bf16(a, b, c, 0, 0, 0);
}

// ---------------- Kernel 1: per-pixel LayerNorm stats (mu, rstd) ----------------
__global__ __launch_bounds__(256) void k_lnstats(
    const float* __restrict__ xl, const float* __restrict__ xr,
    float* __restrict__ muW, float* __restrict__ rsW)
{
  const int bx = blockIdx.x;
  const int side = bx >> 7, rem = bx & 127;
  const int b = rem >> 1, half = rem & 1;
  const float* x = (side ? xr : xl) + (size_t)b * 131072 + half * 512;
  const int t = threadIdx.x;
  const int px = t * 2;
  float s0=0, s1=0, q0=0, q1=0;
#pragma unroll 4
  for (int c = 0; c < 128; ++c) {
    const float2 v = *(const float2*)(x + c*1024 + px);
    s0 += v.x; q0 += v.x*v.x;
    s1 += v.y; q1 += v.y*v.y;
  }
  const int o = (side*64 + b)*1024 + half*512 + px;
  float2 mu, rs;
  mu.x = s0*(1.0f/128.0f); mu.y = s1*(1.0f/128.0f);
  rs.x = rsqrtf(fmaxf(q0*(1.0f/128.0f) - mu.x*mu.x, 0.0f) + 1e-6f);
  rs.y = rsqrtf(fmaxf(q1*(1.0f/128.0f) - mu.y*mu.y, 0.0f) + 1e-6f);
  *(float2*)(muW + o) = mu;
  *(float2*)(rsW + o) = rs;
}

// ---------------- Kernel 1b: weight prep ----------------
// Wq/Wv emitted in K-tiled layout: [side][kb=32][cout=128][64 k] bf16.
__global__ __launch_bounds__(256) void k_wprep(
    const float* __restrict__ lnwl, const float* __restrict__ lnbl,
    const float* __restrict__ lnwr, const float* __restrict__ lnbr,
    const float* __restrict__ Wl1, const float* __restrict__ bl1,
    const float* __restrict__ Wr1, const float* __restrict__ br1,
    const float* __restrict__ Wl2, const float* __restrict__ Wr2,
    unsigned short* __restrict__ Wq, unsigned short* __restrict__ Wv,
    float* __restrict__ bqW)
{
  const int bx = blockIdx.x;
  const int side = bx >> 7, co = bx & 127;
  const float* W1  = side ? Wr1 : Wl1;
  const float* W2  = side ? Wr2 : Wl2;
  const float* b1  = side ? br1 : bl1;
  const float* lnw = side ? lnwr : lnwl;
  const float* lnb = side ? lnbr : lnbl;
  const int t = threadIdx.x;
  const int ci = t >> 1;
  const float lw = lnw[ci], lb = lnb[ci];

  const size_t dsto = (size_t)(side*32 + (t>>3))*8192 + (size_t)co*64 + (t&7)*8;

  const float* src1 = W1 + (size_t)co*2048 + t*8;
  const float4 a0 = *(const float4*)(src1);
  const float4 a1 = *(const float4*)(src1 + 4);
  float part = (a0.x+a0.y+a0.z+a0.w + a1.x+a1.y+a1.z+a1.w) * lb;
  uint4 pkq;
  pkq.x = pk2(a0.x*lw, a0.y*lw); pkq.y = pk2(a0.z*lw, a0.w*lw);
  pkq.z = pk2(a1.x*lw, a1.y*lw); pkq.w = pk2(a1.z*lw, a1.w*lw);
  *(uint4*)(Wq + dsto) = pkq;

  const float* src2 = W2 + (size_t)co*2048 + t*8;
  const float4 c0 = *(const float4*)(src2);
  const float4 c1 = *(const float4*)(src2 + 4);
  uint4 pkv;
  pkv.x = pk2(c0.x, c0.y); pkv.y = pk2(c0.z, c0.w);
  pkv.z = pk2(c1.x, c1.y); pkv.w = pk2(c1.z, c1.w);
  *(uint4*)(Wv + dsto) = pkv;

  __shared__ float red[4];
  float v = part;
  v += __shfl_down(v, 32, 64); v += __shfl_down(v, 16, 64);
  v += __shfl_down(v, 8, 64);  v += __shfl_down(v, 4, 64);
  v += __shfl_down(v, 2, 64);  v += __shfl_down(v, 1, 64);
  if ((t & 63) == 0) red[t >> 6] = v;
  __syncthreads();
  if (t == 0) bqW[side*128 + co] = b1[co] + red[0] + red[1] + red[2] + red[3];
}

// ---------------- Kernel 2: conv GEMM, split-K x4, direct staging ----------------
// grid 1024: bid = (ctype*64+img)*4 + ks. M=64, N=128, K=512 per block (8 x BK=64).
__global__ __launch_bounds__(256) void k_conv(
    const float* __restrict__ xl, const float* __restrict__ xr,
    const unsigned short* __restrict__ Wq, const unsigned short* __restrict__ Wv,
    const float* __restrict__ muW, const float* __restrict__ rsW,
    unsigned short* __restrict__ Cpart)
{
  const int bid = blockIdx.x;
  const int ks = bid & 3;
  const int img = (bid >> 2) & 63;
  const int ctype = bid >> 8;
  const int side = ctype & 1;
  const bool isQ = ctype < 2;
  const float* x = (side ? xr : xl) + (size_t)img * 131072;
  const unsigned short* Bsrc = (isQ ? Wq : Wv) + (size_t)side * 262144;

  const int t = threadIdx.x;
  const int w = t >> 6, l = t & 63, lo = l & 15, g = l >> 4;

  __shared__ __align__(16) unsigned char lds[24576];  // [0,8K) A, [8K,24K) B
  unsigned char* A = lds;
  unsigned char* B = lds + 8192;

  const int cl   = t >> 6;
  const int px0  = (t & 63) * 16;
  const int y    = px0 >> 5;
  const int wr   = y & 3;
  const int pbase = (y >> 2)*8 + ((px0 & 31) >> 2);

  float4 mu4[4], rs4[4];
  if (isQ) {
    const int o = (side*64 + img)*1024 + px0;
#pragma unroll
    for (int i = 0; i < 4; ++i) {
      mu4[i] = *(const float4*)(muW + o + 4*i);
      rs4[i] = *(const float4*)(rsW + o + 4*i);
    }
  }

  const int cout = t >> 1, part = t & 1;
  const int keyB = ((cout ^ (cout >> 3)) & 7) << 4;

  f32x4 acc[4][2];
#pragma unroll
  for (int a = 0; a < 4; ++a) { acc[a][0] = (f32x4)0.0f; acc[a][1] = (f32x4)0.0f; }

  for (int it = 0; it < 8; ++it) {
    const int kb = ks*8 + it;
    __syncthreads();
    {
      const float* xs = x + (size_t)(kb*4 + cl)*1024 + px0;
#pragma unroll
      for (int i = 0; i < 4; ++i) {
        float4 v = *(const float4*)(xs + 4*i);
        if (isQ) {
          v.x = (v.x - mu4[i].x)*rs4[i].x; v.y = (v.y - mu4[i].y)*rs4[i].y;
          v.z = (v.z - mu4[i].z)*rs4[i].z; v.w = (v.w - mu4[i].w)*rs4[i].w;
        }
        const int p = pbase + i;
        int dst = p*128 + cl*32 + wr*8;
        dst ^= ((p ^ (p >> 3)) & 7) << 4;
        *(uint2*)(A + dst) = make_uint2(pk2(v.x, v.y), pk2(v.z, v.w));
      }
    }
    {
      const unsigned short* bs = Bsrc + (size_t)kb*8192 + t*32;
#pragma unroll
      for (int i = 0; i < 4; ++i) {
        const bf16x8 v = *(const bf16x8*)(bs + i*8);
        *(bf16x8*)(B + cout*128 + ((part*64 + i*16) ^ keyB)) = v;
      }
    }
    __syncthreads();
    bf16x8 af[4][2], bfr[2][2];
#pragma unroll
    for (int mf = 0; mf < 4; ++mf) {
      const int row = mf*16 + lo;
      const int key = ((row ^ (row >> 3)) & 7) << 4;
#pragma unroll
      for (int kc = 0; kc < 2; ++kc)
        af[mf][kc] = *(const bf16x8*)(A + row*128 + ((kc*64 + g*16) ^ key));
    }
#pragma unroll
    for (int nf = 0; nf < 2; ++nf) {
      const int row = w*32 + nf*16 + lo;
      const int key = ((row ^ (row >> 3)) & 7) << 4;
#pragma unroll
      for (int kc = 0; kc < 2; ++kc)
        bfr[nf][kc] = *(const bf16x8*)(B + row*128 + ((kc*64 + g*16) ^ key));
    }
    __builtin_amdgcn_s_setprio(1);
#pragma unroll
    for (int kc = 0; kc < 2; ++kc)
#pragma unroll
      for (int nf = 0; nf < 2; ++nf)
#pragma unroll
        for (int mf = 0; mf < 4; ++mf)
          acc[mf][nf] = mfma16(af[mf][kc], bfr[nf][kc], acc[mf][nf]);
    __builtin_amdgcn_s_setprio(0);
  }

  unsigned short* Cp = Cpart + (size_t)bid * 8192;
#pragma unroll
  for (int mf = 0; mf < 4; ++mf)
#pragma unroll
    for (int nf = 0; nf < 2; ++nf) {
      const int c = w*32 + nf*16 + lo;
      const int p0 = mf*16 + g*4;
      *(uint2*)(Cp + c*64 + p0) =
          make_uint2(pk2(acc[mf][nf][0], acc[mf][nf][1]),
                     pk2(acc[mf][nf][2], acc[mf][nf][3]));
    }
}

// ---------------- Kernel 2b: combine conv split-K partials ----------------
__global__ __launch_bounds__(256) void k_convred(
    const unsigned short* __restrict__ Cpart,
    const float* __restrict__ bqW,
    const float* __restrict__ bl2, const float* __restrict__ br2,
    const float* __restrict__ pos,
    unsigned short* __restrict__ Qbf, unsigned short* __restrict__ Vtbf)
{
  const int bid2 = blockIdx.x;
  const int ctype = bid2 >> 6, img = bid2 & 63;
  const int side = ctype & 1;
  const bool isQ = ctype < 2;
  const int t = threadIdx.x;

  __shared__ float S[64][130];

  const int c = t >> 1, p0 = (t & 1) * 32;
  {
    float acc[32];
#pragma unroll
    for (int j = 0; j < 32; ++j) acc[j] = 0.f;
#pragma unroll
    for (int s = 0; s < 4; ++s) {
      const unsigned short* Cp = Cpart + ((size_t)(bid2*4 + s))*8192 + c*64 + p0;
#pragma unroll
      for (int j8 = 0; j8 < 4; ++j8) {
        const bf16x8 v = *(const bf16x8*)(Cp + j8*8);
#pragma unroll
        for (int e = 0; e < 8; ++e)
          acc[j8*8 + e] += bf2f((unsigned short)v[e]);
      }
    }
#pragma unroll
    for (int j = 0; j < 32; ++j) S[p0 + j][c] = acc[j];
  }
  __syncthreads();

  if (isQ) {
    const float* bq = bqW + side*128;
    const int p = t >> 2, c0 = (t & 3) * 32;
    const int rot = (t & 3) * 4;
    uint32_t pk[16];
#pragma unroll
    for (int j2 = 0; j2 < 16; ++j2) {
      const int jj = (j2 + rot) & 15;
      const int ca = c0 + jj*2;
      const float2 sv = *(const float2*)(&S[p][ca]);
      const float va = (sv.x + bq[ca]     + pos[ca*64 + p])     * 0.105112052f;
      const float vb = (sv.y + bq[ca + 1] + pos[(ca+1)*64 + p]) * 0.105112052f;
      pk[jj] = pk2(va, vb);
    }
    unsigned short* Qo = Qbf + (size_t)side*524288 + ((size_t)(img*64 + p))*128 + c0;
    *(uint4*)(Qo)      = make_uint4(pk[0],  pk[1],  pk[2],  pk[3]);
    *(uint4*)(Qo + 8)  = make_uint4(pk[4],  pk[5],  pk[6],  pk[7]);
    *(uint4*)(Qo + 16) = make_uint4(pk[8],  pk[9],  pk[10], pk[11]);
    *(uint4*)(Qo + 24) = make_uint4(pk[12], pk[13], pk[14], pk[15]);
  } else {
    const float* b2 = side ? br2 : bl2;
    const float bb = b2[c];
    uint32_t pk[16];
#pragma unroll
    for (int j2 = 0; j2 < 16; ++j2) {
      const int pa = p0 + j2*2;
      const float va = S[pa][c]     + bb + pos[c*64 + pa];
      const float vb = S[pa + 1][c] + bb + pos[c*64 + pa + 1];
      pk[j2] = pk2(va, vb);
    }
    unsigned short* Vo = Vtbf + (size_t)side*524288 + (size_t)c*4096 + img*64 + p0;
    *(uint4*)(Vo)      = make_uint4(pk[0],  pk[1],  pk[2],  pk[3]);
    *(uint4*)(Vo + 8)  = make_uint4(pk[4],  pk[5],  pk[6],  pk[7]);
    *(uint4*)(Vo + 16) = make_uint4(pk[8],  pk[9],  pk[10], pk[11]);
    *(uint4*)(Vo + 24) = make_uint4(pk[12], pk[13], pk[14], pk[15]);
  }
}

// ---------------- Kernel 3: cross-attention, QBLK=64, split-K x4, dbuf+async stage ----------------
// grid (64 qb, 4 ks, 2 dir). 64 q-rows, 1024 keys/block in 16 tiles of 64.
__global__ __launch_bounds__(256, 2) void k_attn(
    const unsigned short* __restrict__ Qbf,
    const unsigned short* __restrict__ Vtbf,
    float* __restrict__ Opart,   // [2][64][4][64][128] f32
    float* __restrict__ Lpart)   // [2][64][4][64] f32
{
  const int qb = blockIdx.x, ks = blockIdx.y, dir = blockIdx.z;
  const unsigned short* Qp = Qbf  + (size_t)dir*524288;
  const unsigned short* Kp = Qbf  + (size_t)(1-dir)*524288;
  const unsigned short* Vp = Vtbf + (size_t)(1-dir)*524288;

  const int t = threadIdx.x;
  const int w = t >> 6, l = t & 63, lo = l & 15, g = l >> 4;

  // [0,32K): K dbuf (2x16K); [32K,64K): V dbuf (2x16K); [64K,72K): P [64][64]bf16
  __shared__ __align__(16) unsigned char lds[73728];
  unsigned char* ldsP = lds + 65536;
  __shared__ float lred[4][64];

  // Q fragments: 64 rows, kept in registers
  bf16x8 aq[4][4];
#pragma unroll
  for (int mf = 0; mf < 4; ++mf)
#pragma unroll
    for (int kc = 0; kc < 4; ++kc)
      aq[mf][kc] = *(const bf16x8*)(Qp + (size_t)(qb*64 + mf*16 + lo)*128 + kc*32 + g*8);

  f32x4 o[4][2];
#pragma unroll
  for (int a = 0; a < 4; ++a) { o[a][0] = (f32x4)0.0f; o[a][1] = (f32x4)0.0f; }
  float ls[4][4] = {{0,0,0,0},{0,0,0,0},{0,0,0,0},{0,0,0,0}};

  const int kt0 = ks * 16;

  // staging geometry (loop-invariant)
  const int ksrcBase = t ^ ((t >> 4) & 7);          // uint4 index into K tile
  const int vc    = t >> 3;                          // V rows: vc + 32*j
  const int vi16  = (t & 7) * 16;                    // LDS byte slot within V row
  const int vsoff = (vi16 ^ (((t >> 3) & 7) << 4)) >> 1;  // src elem offset

  // prologue: stage tile kt0 directly
  {
    const uint4* src = (const uint4*)(Kp + (size_t)kt0*8192);
#pragma unroll
    for (int j = 0; j < 4; ++j)
      *(uint4*)(lds + (t + 256*j)*16) = src[ksrcBase + 256*j];
#pragma unroll
    for (int j = 0; j < 4; ++j) {
      const int c = vc + 32*j;
      *(uint4*)(lds + 32768 + c*128 + vi16) =
          *(const uint4*)(Vp + (size_t)c*4096 + kt0*64 + vsoff);
    }
  }
  __syncthreads();

  for (int it = 0; it < 16; ++it) {
    const int cur = it & 1;
    unsigned char* curK = lds + cur*16384;
    unsigned char* curV = lds + 32768 + cur*16384;

    // issue next-tile loads into named registers (T14 async-stage)
    uint4 kr0, kr1, kr2, kr3, vr0, vr1, vr2, vr3;
    if (it < 15) {
      const int kt = kt0 + it + 1;
      const uint4* src = (const uint4*)(Kp + (size_t)kt*8192);
      kr0 = src[ksrcBase];
      kr1 = src[ksrcBase + 256];
      kr2 = src[ksrcBase + 512];
      kr3 = src[ksrcBase + 768];
      const unsigned short* vsrc = Vp + (size_t)kt*64 + vsoff;
      vr0 = *(const uint4*)(vsrc + (size_t)(vc     )*4096);
      vr1 = *(const uint4*)(vsrc + (size_t)(vc + 32)*4096);
      vr2 = *(const uint4*)(vsrc + (size_t)(vc + 64)*4096);
      vr3 = *(const uint4*)(vsrc + (size_t)(vc + 96)*4096);
    }

    // QK^T : S[64q][64k], wave w covers keys w*16..+15
    f32x4 s[4];
    s[0] = (f32x4)0.0f; s[1] = (f32x4)0.0f; s[2] = (f32x4)0.0f; s[3] = (f32x4)0.0f;
    const int krow = w*16 + lo;
    const int keyk = (krow & 7) << 4;
    __builtin_amdgcn_s_setprio(1);
#pragma unroll
    for (int kc = 0; kc < 4; ++kc) {
      const bf16x8 bk = *(const bf16x8*)(curK + krow*256 + ((kc*64 + g*16) ^ keyk));
#pragma unroll
      for (int mf = 0; mf < 4; ++mf)
        s[mf] = mfma16(aq[mf][kc], bk, s[mf]);
    }
    __builtin_amdgcn_s_setprio(0);

    // exp (no max: logits small), write P, accumulate denom
#pragma unroll
    for (int mf = 0; mf < 4; ++mf)
#pragma unroll
      for (int rr = 0; rr < 4; ++rr) {
        const float e = __expf(s[mf][rr]);
        ls[mf][rr] += e;
        const int q = mf*16 + g*4 + rr;
        const int inrow = (w*32 + lo*2) ^ ((q & 7) << 4);
        *(unsigned short*)(ldsP + q*128 + inrow) = f2bf(e);
      }
    __syncthreads();   // P visible

    // PV : O[64q][128c], wave w covers c = w*32..+31
    __builtin_amdgcn_s_setprio(1);
#pragma unroll
    for (int kd = 0; kd < 2; ++kd) {
      bf16x8 pa[4];
#pragma unroll
      for (int mf = 0; mf < 4; ++mf) {
        const int q = mf*16 + lo;
        pa[mf] = *(const bf16x8*)(ldsP + q*128 + ((kd*64 + g*16) ^ ((q & 7) << 4)));
      }
#pragma unroll
      for (int nf = 0; nf < 2; ++nf) {
        const int c = w*32 + nf*16 + lo;
        const bf16x8 bv = *(const bf16x8*)(curV + c*128 + ((kd*64 + g*16) ^ ((c & 7) << 4)));
#pragma unroll
        for (int mf = 0; mf < 4; ++mf)
          o[mf][nf] = mfma16(pa[mf], bv, o[mf][nf]);
      }
    }
    __builtin_amdgcn_s_setprio(0);

    // write staged regs -> other buffer
    if (it < 15) {
      unsigned char* nK = lds + (cur ^ 1)*16384;
      unsigned char* nV = lds + 32768 + (cur ^ 1)*16384;
      *(uint4*)(nK + (t      )*16) = kr0;
      *(uint4*)(nK + (t + 256)*16) = kr1;
      *(uint4*)(nK + (t + 512)*16) = kr2;
      *(uint4*)(nK + (t + 768)*16) = kr3;
      *(uint4*)(nV + (vc     )*128 + vi16) = vr0;
      *(uint4*)(nV + (vc + 32)*128 + vi16) = vr1;
      *(uint4*)(nV + (vc + 64)*128 + vi16) = vr2;
      *(uint4*)(nV + (vc + 96)*128 + vi16) = vr3;
    }
    __syncthreads();   // next buffer ready; P consumed
  }

  // denominator reduce: 16 key-lanes, then across waves
#pragma unroll
  for (int mf = 0; mf < 4; ++mf)
#pragma unroll
    for (int rr = 0; rr < 4; ++rr) {
      float v = ls[mf][rr];
      v += __shfl_xor(v, 1, 64);
      v += __shfl_xor(v, 2, 64);
      v += __shfl_xor(v, 4, 64);
      v += __shfl_xor(v, 8, 64);
      ls[mf][rr] = v;
    }
  if (lo == 0) {
#pragma unroll
    for (int mf = 0; mf < 4; ++mf)
#pragma unroll
      for (int rr = 0; rr < 4; ++rr)
        lred[w][mf*16 + g*4 + rr] = ls[mf][rr];
  }
  __syncthreads();

  float* Ob = Opart + (((size_t)dir*64 + qb)*4 + ks)*64*128;
#pragma unroll
  for (int mf = 0; mf < 4; ++mf)
#pragma unroll
    for (int nf = 0; nf < 2; ++nf) {
      const int c = w*32 + nf*16 + lo;
#pragma unroll
      for (int rr = 0; rr < 4; ++rr) {
        const int q = mf*16 + g*4 + rr;
        Ob[q*128 + c] = o[mf][nf][rr];
      }
    }
  if (t < 64)
    Lpart[(((size_t)dir*64 + qb)*4 + ks)*64 + t] =
        lred[0][t] + lred[1][t] + lred[2][t] + lred[3][t];
}

// ---------------- Kernel 3b: combine split-K partials -> F bf16 ----------------
// grid 256: bid = dir*128 + rb (rb = 32-row chunk of 4096 rows)
__global__ __launch_bounds__(256) void k_reduce(
    const float* __restrict__ Opart, const float* __restrict__ Lpart,
    unsigned short* __restrict__ Fbf)
{
  const int bid = blockIdx.x;
  const int dir = bid >> 7, rb = bid & 127;
  const int t = threadIdx.x;
  const int qr = t >> 3;
  const int cs = (t & 7) * 16;
  const int r  = rb*32 + qr;
  const int qb = r >> 6, q = r & 63;
  const size_t pb = ((size_t)dir*64 + qb)*4;
  float acc[16];
#pragma unroll
  for (int i = 0; i < 16; ++i) acc[i] = 0.f;
  float lsum = 0.f;
#pragma unroll
  for (int s = 0; s < 4; ++s) {
    const float* Ob = Opart + ((pb + s)*64 + q)*128 + cs;
#pragma unroll
    for (int i = 0; i < 16; i += 4) {
      const float4 v = *(const float4*)(Ob + i);
      acc[i] += v.x; acc[i+1] += v.y; acc[i+2] += v.z; acc[i+3] += v.w;
    }
    lsum += Lpart[(pb + s)*64 + q];
  }
  const float inv = 1.0f / lsum;
  uint32_t pkw[8];
#pragma unroll
  for (int i = 0; i < 8; ++i) pkw[i] = pk2(acc[2*i]*inv, acc[2*i+1]*inv);
  unsigned short* Fo = Fbf + (size_t)dir*524288 + (size_t)r*128 + cs;
  *(uint4*)(Fo)     = make_uint4(pkw[0], pkw[1], pkw[2], pkw[3]);
  *(uint4*)(Fo + 8) = make_uint4(pkw[4], pkw[5], pkw[6], pkw[7]);
}

// ---------------- Kernel 4: projection + pixel-shuffle + residual ----------------
__global__ __launch_bounds__(256) void k_proj(
    const unsigned short* __restrict__ Fbf,
    const float* __restrict__ Wl3, const float* __restrict__ bl3,
    const float* __restrict__ Wr3, const float* __restrict__ br3,
    const float* __restrict__ beta, const float* __restrict__ gamma,
    const float* __restrict__ xl, const float* __restrict__ xr,
    float* __restrict__ out)
{
  const int nb = blockIdx.x, mb = blockIdx.y, side = blockIdx.z;
  const unsigned short* F = Fbf + (size_t)side*524288;
  const float* W3  = side ? Wr3 : Wl3;
  const float* b3  = side ? br3 : bl3;
  const float* scl = side ? gamma : beta;
  const float* xin = side ? xr : xl;
  float* op = out + (size_t)side*8388608;

  const int t = threadIdx.x;
  const int w = t >> 6, l = t & 63, lo = l & 15, g = l >> 4;

  __shared__ __align__(16) unsigned char Ft[16384];
  __shared__ __align__(16) unsigned char B3[32768];

  {
    const uint4* src = (const uint4*)(F + (size_t)mb*8192);
#pragma unroll
    for (int j = 0; j < 4; ++j) {
      const int idx = t + 256*j;
      const int dst = idx*16;
      const int row = dst >> 8;
      *(uint4*)(Ft + dst) = src[(dst ^ ((row & 7) << 4)) >> 4];
    }
  }
  {
    const int nl = t >> 1, half = t & 1;
    const float* wsrc = W3 + (size_t)(nb*128 + nl)*128 + half*64;
#pragma unroll
    for (int ch = 0; ch < 8; ++ch) {
      const float4 v0 = *(const float4*)(wsrc + ch*8);
      const float4 v1 = *(const float4*)(wsrc + ch*8 + 4);
      uint4 pk;
      pk.x = pk2(v0.x,v0.y); pk.y = pk2(v0.z,v0.w);
      pk.z = pk2(v1.x,v1.y); pk.w = pk2(v1.z,v1.w);
      const int inrow = (half*128 + ch*16) ^ ((nl & 7) << 4);
      *(uint4*)(B3 + nl*256 + inrow) = pk;
    }
  }
  __syncthreads();

  f32x4 acc[4][2];
#pragma unroll
  for (int a=0;a<4;a++) { acc[a][0] = (f32x4)0.0f; acc[a][1] = (f32x4)0.0f; }

  bf16x8 af[4][4];
#pragma unroll
  for (int mf = 0; mf < 4; ++mf) {
    const int row = mf*16 + lo;
#pragma unroll
    for (int kc = 0; kc < 4; ++kc)
      af[mf][kc] = *(const bf16x8*)(Ft + row*256 + ((kc*64 + g*16) ^ ((row & 7) << 4)));
  }
#pragma unroll
  for (int kc = 0; kc < 4; ++kc)
#pragma unroll
    for (int nf = 0; nf < 2; ++nf) {
      const int n = w*32 + nf*16 + lo;
      const bf16x8 bb = *(const bf16x8*)(B3 + n*256 + ((kc*64 + g*16) ^ ((n & 7) << 4)));
#pragma unroll
      for (int mf = 0; mf < 4; ++mf)
        acc[mf][nf] = mfma16(af[mf][kc], bb, acc[mf][nf]);
    }

#pragma unroll
  for (int mf = 0; mf < 4; ++mf)
#pragma unroll
    for (int nf = 0; nf < 2; ++nf) {
      const int n16 = nb*128 + w*32 + nf*16 + lo;
      const int c = n16 >> 4, r4 = (n16 >> 2) & 3, sc = n16 & 3;
      const float scc = scl[c];
      const float bb3 = b3[n16];
#pragma unroll
      for (int rr = 0; rr < 4; ++rr) {
        const int pi = mf*16 + g*4 + rr;
        const int h = pi >> 3, wc = pi & 7;
        const size_t oidx = ((size_t)(mb*128 + c))*1024 + (size_t)(h*4 + r4)*32 + wc*4 + sc;
        op[oidx] = xin[oidx] + scc*(acc[mf][nf][rr] + bb3);
      }
    }
}

extern "C" void kernel_launch(void* const* d_in, const int* in_sizes, int n_in,
                              void* d_out, int out_size, void* d_ws, size_t ws_size,
                              hipStream_t stream) {
  (void)in_sizes; (void)n_in; (void)out_size; (void)ws_size;
  const float* xl   = (const float*)d_in[0];
  const float* xr   = (const float*)d_in[1];
  const float* lnwl = (const float*)d_in[2];
  const float* lnbl = (const float*)d_in[3];
  const float* lnwr = (const float*)d_in[4];
  const float* lnbr = (const float*)d_in[5];
  const float* Wl1  = (const float*)d_in[6];
  const float* bl1  = (const float*)d_in[7];
  const float* Wr1  = (const float*)d_in[8];
  const float* br1  = (const float*)d_in[9];
  const float* Wl2  = (const float*)d_in[10];
  const float* bl2  = (const float*)d_in[11];
  const float* Wr2  = (const float*)d_in[12];
  const float* br2  = (const float*)d_in[13];
  const float* pos  = (const float*)d_in[14];
  const float* beta = (const float*)d_in[15];
  const float* gamma= (const float*)d_in[16];
  const float* Wl3  = (const float*)d_in[17];
  const float* bl3  = (const float*)d_in[18];
  const float* Wr3  = (const float*)d_in[19];
  const float* br3  = (const float*)d_in[20];

  float* muW = (float*)d_ws;                            // [2][64][1024]
  float* rsW = muW + 131072;                            // [2][64][1024]
  float* bqW = rsW + 131072;                            // [2][128]
  unsigned short* Wq   = (unsigned short*)(bqW + 256);  // [2][32][128][64]
  unsigned short* Wv   = Wq + 524288;                   // [2][32][128][64]
  unsigned short* Qbf  = Wv + 524288;                   // [2][4096][128]
  unsigned short* Vtbf = Qbf + 1048576;                 // [2][128][4096]
  unsigned short* Fbf  = Vtbf + 1048576;                // [2][4096][128]
  unsigned short* Cpart = Fbf + 1048576;                // [1024][128][64] bf16 (16.8MB)
  float* Opart = (float*)Cpart;                         // alias: [2][64][4][64][128] f32
  float* Lpart = (float*)(Cpart + 8388608);             // [2][64][4][64] f32

  k_lnstats<<<256, 256, 0, stream>>>(xl, xr, muW, rsW);
  k_wprep<<<256, 256, 0, stream>>>(lnwl, lnbl, lnwr, lnbr,
      Wl1, bl1, Wr1, br1, Wl2, Wr2, Wq, Wv, bqW);
  k_conv<<<1024, 256, 0, stream>>>(xl, xr, Wq, Wv, muW, rsW, Cpart);
  k_convred<<<256, 256, 0, stream>>>(Cpart, bqW, bl2, br2, pos, Qbf, Vtbf);
  k_attn<<<dim3(64, 4, 2), 256, 0, stream>>>(Qbf, Vtbf, Opart, Lpart);
  k_reduce<<<256, 256, 0, stream>>>(Opart, Lpart, Fbf);
  k_proj<<<dim3(16, 64, 2), 256, 0, stream>>>(Fbf, Wl3, bl3, Wr3, br3,
      beta, gamma, xl, xr, (float*)d_out);
}

// Round 9
// 121.583 us; speedup vs baseline: 2.3290x; 1.1167x over previous
//
#include <hip/hip_runtime.h>
#include <stdint.h>

using bf16x8 = __attribute__((ext_vector_type(8))) short;
using f32x4  = __attribute__((ext_vector_type(4))) float;

__device__ __forceinline__ unsigned short f2bf(float f) {
  union { float f; uint32_t u; } v; v.f = f;
  uint32_t r = v.u + 0x7FFFu + ((v.u >> 16) & 1u);
  return (unsigned short)(r >> 16);
}
__device__ __forceinline__ uint32_t pk2(float a, float b) {
  return (uint32_t)f2bf(a) | ((uint32_t)f2bf(b) << 16);
}
__device__ __forceinline__ float bf2f(unsigned short s) {
  union { uint32_t u; float f; } v; v.u = ((uint32_t)s) << 16;
  return v.f;
}
__device__ __forceinline__ f32x4 mfma16(bf16x8 a, bf16x8 b, f32x4 c) {
  return __builtin_amdgcn_mfma_f32_16x16x32_bf16(a, b, c, 0, 0, 0);
}

// ---------------- Kernel 1: per-pixel LayerNorm stats (mu, rstd) ----------------
__global__ __launch_bounds__(256) void k_lnstats(
    const float* __restrict__ xl, const float* __restrict__ xr,
    float* __restrict__ muW, float* __restrict__ rsW)
{
  const int bx = blockIdx.x;
  const int side = bx >> 7, rem = bx & 127;
  const int b = rem >> 1, half = rem & 1;
  const float* x = (side ? xr : xl) + (size_t)b * 131072 + half * 512;
  const int t = threadIdx.x;
  const int px = t * 2;
  float s0=0, s1=0, q0=0, q1=0;
#pragma unroll 4
  for (int c = 0; c < 128; ++c) {
    const float2 v = *(const float2*)(x + c*1024 + px);
    s0 += v.x; q0 += v.x*v.x;
    s1 += v.y; q1 += v.y*v.y;
  }
  const int o = (side*64 + b)*1024 + half*512 + px;
  float2 mu, rs;
  mu.x = s0*(1.0f/128.0f); mu.y = s1*(1.0f/128.0f);
  rs.x = rsqrtf(fmaxf(q0*(1.0f/128.0f) - mu.x*mu.x, 0.0f) + 1e-6f);
  rs.y = rsqrtf(fmaxf(q1*(1.0f/128.0f) - mu.y*mu.y, 0.0f) + 1e-6f);
  *(float2*)(muW + o) = mu;
  *(float2*)(rsW + o) = rs;
}

// ---------------- Kernel 1b: weight prep (conv weights) ----------------
__global__ __launch_bounds__(256) void k_wprep(
    const float* __restrict__ lnwl, const float* __restrict__ lnbl,
    const float* __restrict__ lnwr, const float* __restrict__ lnbr,
    const float* __restrict__ Wl1, const float* __restrict__ bl1,
    const float* __restrict__ Wr1, const float* __restrict__ br1,
    const float* __restrict__ Wl2, const float* __restrict__ Wr2,
    unsigned short* __restrict__ Wq, unsigned short* __restrict__ Wv,
    float* __restrict__ bqW)
{
  const int bx = blockIdx.x;
  const int side = bx >> 7, co = bx & 127;
  const float* W1  = side ? Wr1 : Wl1;
  const float* W2  = side ? Wr2 : Wl2;
  const float* b1  = side ? br1 : bl1;
  const float* lnw = side ? lnwr : lnwl;
  const float* lnb = side ? lnbr : lnbl;
  const int t = threadIdx.x;
  const int ci = t >> 1;
  const float lw = lnw[ci], lb = lnb[ci];

  const size_t dsto = (size_t)(side*32 + (t>>3))*8192 + (size_t)co*64 + (t&7)*8;

  const float* src1 = W1 + (size_t)co*2048 + t*8;
  const float4 a0 = *(const float4*)(src1);
  const float4 a1 = *(const float4*)(src1 + 4);
  float part = (a0.x+a0.y+a0.z+a0.w + a1.x+a1.y+a1.z+a1.w) * lb;
  uint4 pkq;
  pkq.x = pk2(a0.x*lw, a0.y*lw); pkq.y = pk2(a0.z*lw, a0.w*lw);
  pkq.z = pk2(a1.x*lw, a1.y*lw); pkq.w = pk2(a1.z*lw, a1.w*lw);
  *(uint4*)(Wq + dsto) = pkq;

  const float* src2 = W2 + (size_t)co*2048 + t*8;
  const float4 c0 = *(const float4*)(src2);
  const float4 c1 = *(const float4*)(src2 + 4);
  uint4 pkv;
  pkv.x = pk2(c0.x, c0.y); pkv.y = pk2(c0.z, c0.w);
  pkv.z = pk2(c1.x, c1.y); pkv.w = pk2(c1.z, c1.w);
  *(uint4*)(Wv + dsto) = pkv;

  __shared__ float red[4];
  float v = part;
  v += __shfl_down(v, 32, 64); v += __shfl_down(v, 16, 64);
  v += __shfl_down(v, 8, 64);  v += __shfl_down(v, 4, 64);
  v += __shfl_down(v, 2, 64);  v += __shfl_down(v, 1, 64);
  if ((t & 63) == 0) red[t >> 6] = v;
  __syncthreads();
  if (t == 0) bqW[side*128 + co] = b1[co] + red[0] + red[1] + red[2] + red[3];
}

// ---------------- Kernel 1c: W3 -> bf16 flat copy ----------------
__global__ __launch_bounds__(256) void k_w3prep(
    const float* __restrict__ Wl3, const float* __restrict__ Wr3,
    unsigned short* __restrict__ W3bf)
{
  const int b = blockIdx.x;
  const float* src = (b < 256 ? Wl3 : Wr3) + (size_t)(b & 255) * 1024;
  const int t = threadIdx.x;
  const float4 v = *(const float4*)(src + t*4);
  *(uint2*)(W3bf + (size_t)b*1024 + t*4) = make_uint2(pk2(v.x, v.y), pk2(v.z, v.w));
}

// ---------------- Kernel 2: conv GEMM, split-K x4, direct staging ----------------
__global__ __launch_bounds__(256) void k_conv(
    const float* __restrict__ xl, const float* __restrict__ xr,
    const unsigned short* __restrict__ Wq, const unsigned short* __restrict__ Wv,
    const float* __restrict__ muW, const float* __restrict__ rsW,
    unsigned short* __restrict__ Cpart)
{
  const int bid = blockIdx.x;
  const int ks = bid & 3;
  const int img = (bid >> 2) & 63;
  const int ctype = bid >> 8;
  const int side = ctype & 1;
  const bool isQ = ctype < 2;
  const float* x = (side ? xr : xl) + (size_t)img * 131072;
  const unsigned short* Bsrc = (isQ ? Wq : Wv) + (size_t)side * 262144;

  const int t = threadIdx.x;
  const int w = t >> 6, l = t & 63, lo = l & 15, g = l >> 4;

  __shared__ __align__(16) unsigned char lds[24576];
  unsigned char* A = lds;
  unsigned char* B = lds + 8192;

  const int cl   = t >> 6;
  const int px0  = (t & 63) * 16;
  const int y    = px0 >> 5;
  const int wr   = y & 3;
  const int pbase = (y >> 2)*8 + ((px0 & 31) >> 2);

  float4 mu4[4], rs4[4];
  if (isQ) {
    const int o = (side*64 + img)*1024 + px0;
#pragma unroll
    for (int i = 0; i < 4; ++i) {
      mu4[i] = *(const float4*)(muW + o + 4*i);
      rs4[i] = *(const float4*)(rsW + o + 4*i);
    }
  }

  const int cout = t >> 1, part = t & 1;
  const int keyB = ((cout ^ (cout >> 3)) & 7) << 4;

  f32x4 acc[4][2];
#pragma unroll
  for (int a = 0; a < 4; ++a) { acc[a][0] = (f32x4)0.0f; acc[a][1] = (f32x4)0.0f; }

  for (int it = 0; it < 8; ++it) {
    const int kb = ks*8 + it;
    __syncthreads();
    {
      const float* xs = x + (size_t)(kb*4 + cl)*1024 + px0;
#pragma unroll
      for (int i = 0; i < 4; ++i) {
        float4 v = *(const float4*)(xs + 4*i);
        if (isQ) {
          v.x = (v.x - mu4[i].x)*rs4[i].x; v.y = (v.y - mu4[i].y)*rs4[i].y;
          v.z = (v.z - mu4[i].z)*rs4[i].z; v.w = (v.w - mu4[i].w)*rs4[i].w;
        }
        const int p = pbase + i;
        int dst = p*128 + cl*32 + wr*8;
        dst ^= ((p ^ (p >> 3)) & 7) << 4;
        *(uint2*)(A + dst) = make_uint2(pk2(v.x, v.y), pk2(v.z, v.w));
      }
    }
    {
      const unsigned short* bs = Bsrc + (size_t)kb*8192 + t*32;
#pragma unroll
      for (int i = 0; i < 4; ++i) {
        const bf16x8 v = *(const bf16x8*)(bs + i*8);
        *(bf16x8*)(B + cout*128 + ((part*64 + i*16) ^ keyB)) = v;
      }
    }
    __syncthreads();
    bf16x8 af[4][2], bfr[2][2];
#pragma unroll
    for (int mf = 0; mf < 4; ++mf) {
      const int row = mf*16 + lo;
      const int key = ((row ^ (row >> 3)) & 7) << 4;
#pragma unroll
      for (int kc = 0; kc < 2; ++kc)
        af[mf][kc] = *(const bf16x8*)(A + row*128 + ((kc*64 + g*16) ^ key));
    }
#pragma unroll
    for (int nf = 0; nf < 2; ++nf) {
      const int row = w*32 + nf*16 + lo;
      const int key = ((row ^ (row >> 3)) & 7) << 4;
#pragma unroll
      for (int kc = 0; kc < 2; ++kc)
        bfr[nf][kc] = *(const bf16x8*)(B + row*128 + ((kc*64 + g*16) ^ key));
    }
    __builtin_amdgcn_s_setprio(1);
#pragma unroll
    for (int kc = 0; kc < 2; ++kc)
#pragma unroll
      for (int nf = 0; nf < 2; ++nf)
#pragma unroll
        for (int mf = 0; mf < 4; ++mf)
          acc[mf][nf] = mfma16(af[mf][kc], bfr[nf][kc], acc[mf][nf]);
    __builtin_amdgcn_s_setprio(0);
  }

  unsigned short* Cp = Cpart + (size_t)bid * 8192;
#pragma unroll
  for (int mf = 0; mf < 4; ++mf)
#pragma unroll
    for (int nf = 0; nf < 2; ++nf) {
      const int c = w*32 + nf*16 + lo;
      const int p0 = mf*16 + g*4;
      *(uint2*)(Cp + c*64 + p0) =
          make_uint2(pk2(acc[mf][nf][0], acc[mf][nf][1]),
                     pk2(acc[mf][nf][2], acc[mf][nf][3]));
    }
}

// ---------------- Kernel 2b: combine conv split-K partials ----------------
__global__ __launch_bounds__(256) void k_convred(
    const unsigned short* __restrict__ Cpart,
    const float* __restrict__ bqW,
    const float* __restrict__ bl2, const float* __restrict__ br2,
    const float* __restrict__ pos,
    unsigned short* __restrict__ Qbf, unsigned short* __restrict__ Vtbf)
{
  const int bid2 = blockIdx.x;
  const int ctype = bid2 >> 6, img = bid2 & 63;
  const int side = ctype & 1;
  const bool isQ = ctype < 2;
  const int t = threadIdx.x;

  __shared__ float S[64][130];

  const int c = t >> 1, p0 = (t & 1) * 32;
  {
    float acc[32];
#pragma unroll
    for (int j = 0; j < 32; ++j) acc[j] = 0.f;
#pragma unroll
    for (int s = 0; s < 4; ++s) {
      const unsigned short* Cp = Cpart + ((size_t)(bid2*4 + s))*8192 + c*64 + p0;
#pragma unroll
      for (int j8 = 0; j8 < 4; ++j8) {
        const bf16x8 v = *(const bf16x8*)(Cp + j8*8);
#pragma unroll
        for (int e = 0; e < 8; ++e)
          acc[j8*8 + e] += bf2f((unsigned short)v[e]);
      }
    }
#pragma unroll
    for (int j = 0; j < 32; ++j) S[p0 + j][c] = acc[j];
  }
  __syncthreads();

  if (isQ) {
    const float* bq = bqW + side*128;
    const int p = t >> 2, c0 = (t & 3) * 32;
    const int rot = (t & 3) * 4;
    uint32_t pk[16];
#pragma unroll
    for (int j2 = 0; j2 < 16; ++j2) {
      const int jj = (j2 + rot) & 15;
      const int ca = c0 + jj*2;
      const float2 sv = *(const float2*)(&S[p][ca]);
      const float va = (sv.x + bq[ca]     + pos[ca*64 + p])     * 0.105112052f;
      const float vb = (sv.y + bq[ca + 1] + pos[(ca+1)*64 + p]) * 0.105112052f;
      pk[jj] = pk2(va, vb);
    }
    unsigned short* Qo = Qbf + (size_t)side*524288 + ((size_t)(img*64 + p))*128 + c0;
    *(uint4*)(Qo)      = make_uint4(pk[0],  pk[1],  pk[2],  pk[3]);
    *(uint4*)(Qo + 8)  = make_uint4(pk[4],  pk[5],  pk[6],  pk[7]);
    *(uint4*)(Qo + 16) = make_uint4(pk[8],  pk[9],  pk[10], pk[11]);
    *(uint4*)(Qo + 24) = make_uint4(pk[12], pk[13], pk[14], pk[15]);
  } else {
    const float* b2 = side ? br2 : bl2;
    const float bb = b2[c];
    uint32_t pk[16];
#pragma unroll
    for (int j2 = 0; j2 < 16; ++j2) {
      const int pa = p0 + j2*2;
      const float va = S[pa][c]     + bb + pos[c*64 + pa];
      const float vb = S[pa + 1][c] + bb + pos[c*64 + pa + 1];
      pk[j2] = pk2(va, vb);
    }
    unsigned short* Vo = Vtbf + (size_t)side*524288 + (size_t)c*4096 + img*64 + p0;
    *(uint4*)(Vo)      = make_uint4(pk[0],  pk[1],  pk[2],  pk[3]);
    *(uint4*)(Vo + 8)  = make_uint4(pk[4],  pk[5],  pk[6],  pk[7]);
    *(uint4*)(Vo + 16) = make_uint4(pk[8],  pk[9],  pk[10], pk[11]);
    *(uint4*)(Vo + 24) = make_uint4(pk[12], pk[13], pk[14], pk[15]);
  }
}

// ---------------- Kernel 3: cross-attention, QBLK=64, split-K x4, dbuf+async stage ----------------
__global__ __launch_bounds__(256, 2) void k_attn(
    const unsigned short* __restrict__ Qbf,
    const unsigned short* __restrict__ Vtbf,
    float* __restrict__ Opart,   // [2][64][4][64][128] f32
    float* __restrict__ Lpart)   // [2][64][4][64] f32
{
  const int qb = blockIdx.x, ks = blockIdx.y, dir = blockIdx.z;
  const unsigned short* Qp = Qbf  + (size_t)dir*524288;
  const unsigned short* Kp = Qbf  + (size_t)(1-dir)*524288;
  const unsigned short* Vp = Vtbf + (size_t)(1-dir)*524288;

  const int t = threadIdx.x;
  const int w = t >> 6, l = t & 63, lo = l & 15, g = l >> 4;

  __shared__ __align__(16) unsigned char lds[73728];
  unsigned char* ldsP = lds + 65536;
  __shared__ float lred[4][64];

  bf16x8 aq[4][4];
#pragma unroll
  for (int mf = 0; mf < 4; ++mf)
#pragma unroll
    for (int kc = 0; kc < 4; ++kc)
      aq[mf][kc] = *(const bf16x8*)(Qp + (size_t)(qb*64 + mf*16 + lo)*128 + kc*32 + g*8);

  f32x4 o[4][2];
#pragma unroll
  for (int a = 0; a < 4; ++a) { o[a][0] = (f32x4)0.0f; o[a][1] = (f32x4)0.0f; }
  float ls[4][4] = {{0,0,0,0},{0,0,0,0},{0,0,0,0},{0,0,0,0}};

  const int kt0 = ks * 16;

  const int ksrcBase = t ^ ((t >> 4) & 7);
  const int vc    = t >> 3;
  const int vi16  = (t & 7) * 16;
  const int vsoff = (vi16 ^ (((t >> 3) & 7) << 4)) >> 1;

  {
    const uint4* src = (const uint4*)(Kp + (size_t)kt0*8192);
#pragma unroll
    for (int j = 0; j < 4; ++j)
      *(uint4*)(lds + (t + 256*j)*16) = src[ksrcBase + 256*j];
#pragma unroll
    for (int j = 0; j < 4; ++j) {
      const int c = vc + 32*j;
      *(uint4*)(lds + 32768 + c*128 + vi16) =
          *(const uint4*)(Vp + (size_t)c*4096 + kt0*64 + vsoff);
    }
  }
  __syncthreads();

  for (int it = 0; it < 16; ++it) {
    const int cur = it & 1;
    unsigned char* curK = lds + cur*16384;
    unsigned char* curV = lds + 32768 + cur*16384;

    uint4 kr0, kr1, kr2, kr3, vr0, vr1, vr2, vr3;
    if (it < 15) {
      const int kt = kt0 + it + 1;
      const uint4* src = (const uint4*)(Kp + (size_t)kt*8192);
      kr0 = src[ksrcBase];
      kr1 = src[ksrcBase + 256];
      kr2 = src[ksrcBase + 512];
      kr3 = src[ksrcBase + 768];
      const unsigned short* vsrc = Vp + (size_t)kt*64 + vsoff;
      vr0 = *(const uint4*)(vsrc + (size_t)(vc     )*4096);
      vr1 = *(const uint4*)(vsrc + (size_t)(vc + 32)*4096);
      vr2 = *(const uint4*)(vsrc + (size_t)(vc + 64)*4096);
      vr3 = *(const uint4*)(vsrc + (size_t)(vc + 96)*4096);
    }

    f32x4 s[4];
    s[0] = (f32x4)0.0f; s[1] = (f32x4)0.0f; s[2] = (f32x4)0.0f; s[3] = (f32x4)0.0f;
    const int krow = w*16 + lo;
    const int keyk = (krow & 7) << 4;
    __builtin_amdgcn_s_setprio(1);
#pragma unroll
    for (int kc = 0; kc < 4; ++kc) {
      const bf16x8 bk = *(const bf16x8*)(curK + krow*256 + ((kc*64 + g*16) ^ keyk));
#pragma unroll
      for (int mf = 0; mf < 4; ++mf)
        s[mf] = mfma16(aq[mf][kc], bk, s[mf]);
    }
    __builtin_amdgcn_s_setprio(0);

#pragma unroll
    for (int mf = 0; mf < 4; ++mf)
#pragma unroll
      for (int rr = 0; rr < 4; ++rr) {
        const float e = __expf(s[mf][rr]);
        ls[mf][rr] += e;
        const int q = mf*16 + g*4 + rr;
        const int inrow = (w*32 + lo*2) ^ ((q & 7) << 4);
        *(unsigned short*)(ldsP + q*128 + inrow) = f2bf(e);
      }
    __syncthreads();

    __builtin_amdgcn_s_setprio(1);
#pragma unroll
    for (int kd = 0; kd < 2; ++kd) {
      bf16x8 pa[4];
#pragma unroll
      for (int mf = 0; mf < 4; ++mf) {
        const int q = mf*16 + lo;
        pa[mf] = *(const bf16x8*)(ldsP + q*128 + ((kd*64 + g*16) ^ ((q & 7) << 4)));
      }
#pragma unroll
      for (int nf = 0; nf < 2; ++nf) {
        const int c = w*32 + nf*16 + lo;
        const bf16x8 bv = *(const bf16x8*)(curV + c*128 + ((kd*64 + g*16) ^ ((c & 7) << 4)));
#pragma unroll
        for (int mf = 0; mf < 4; ++mf)
          o[mf][nf] = mfma16(pa[mf], bv, o[mf][nf]);
      }
    }
    __builtin_amdgcn_s_setprio(0);

    if (it < 15) {
      unsigned char* nK = lds + (cur ^ 1)*16384;
      unsigned char* nV = lds + 32768 + (cur ^ 1)*16384;
      *(uint4*)(nK + (t      )*16) = kr0;
      *(uint4*)(nK + (t + 256)*16) = kr1;
      *(uint4*)(nK + (t + 512)*16) = kr2;
      *(uint4*)(nK + (t + 768)*16) = kr3;
      *(uint4*)(nV + (vc     )*128 + vi16) = vr0;
      *(uint4*)(nV + (vc + 32)*128 + vi16) = vr1;
      *(uint4*)(nV + (vc + 64)*128 + vi16) = vr2;
      *(uint4*)(nV + (vc + 96)*128 + vi16) = vr3;
    }
    __syncthreads();
  }

#pragma unroll
  for (int mf = 0; mf < 4; ++mf)
#pragma unroll
    for (int rr = 0; rr < 4; ++rr) {
      float v = ls[mf][rr];
      v += __shfl_xor(v, 1, 64);
      v += __shfl_xor(v, 2, 64);
      v += __shfl_xor(v, 4, 64);
      v += __shfl_xor(v, 8, 64);
      ls[mf][rr] = v;
    }
  if (lo == 0) {
#pragma unroll
    for (int mf = 0; mf < 4; ++mf)
#pragma unroll
      for (int rr = 0; rr < 4; ++rr)
        lred[w][mf*16 + g*4 + rr] = ls[mf][rr];
  }
  __syncthreads();

  float* Ob = Opart + (((size_t)dir*64 + qb)*4 + ks)*64*128;
#pragma unroll
  for (int mf = 0; mf < 4; ++mf)
#pragma unroll
    for (int nf = 0; nf < 2; ++nf) {
      const int c = w*32 + nf*16 + lo;
#pragma unroll
      for (int rr = 0; rr < 4; ++rr) {
        const int q = mf*16 + g*4 + rr;
        Ob[q*128 + c] = o[mf][nf][rr];
      }
    }
  if (t < 64)
    Lpart[(((size_t)dir*64 + qb)*4 + ks)*64 + t] =
        lred[0][t] + lred[1][t] + lred[2][t] + lred[3][t];
}

// ---------------- Kernel 3b: combine split-K partials -> F bf16 ----------------
__global__ __launch_bounds__(256) void k_reduce(
    const float* __restrict__ Opart, const float* __restrict__ Lpart,
    unsigned short* __restrict__ Fbf)
{
  const int bid = blockIdx.x;
  const int dir = bid >> 7, rb = bid & 127;
  const int t = threadIdx.x;
  const int qr = t >> 3;
  const int cs = (t & 7) * 16;
  const int r  = rb*32 + qr;
  const int qb = r >> 6, q = r & 63;
  const size_t pb = ((size_t)dir*64 + qb)*4;
  float acc[16];
#pragma unroll
  for (int i = 0; i < 16; ++i) acc[i] = 0.f;
  float lsum = 0.f;
#pragma unroll
  for (int s = 0; s < 4; ++s) {
    const float* Ob = Opart + ((pb + s)*64 + q)*128 + cs;
#pragma unroll
    for (int i = 0; i < 16; i += 4) {
      const float4 v = *(const float4*)(Ob + i);
      acc[i] += v.x; acc[i+1] += v.y; acc[i+2] += v.z; acc[i+3] += v.w;
    }
    lsum += Lpart[(pb + s)*64 + q];
  }
  const float inv = 1.0f / lsum;
  uint32_t pkw[8];
#pragma unroll
  for (int i = 0; i < 8; ++i) pkw[i] = pk2(acc[2*i]*inv, acc[2*i+1]*inv);
  unsigned short* Fo = Fbf + (size_t)dir*524288 + (size_t)r*128 + cs;
  *(uint4*)(Fo)     = make_uint4(pkw[0], pkw[1], pkw[2], pkw[3]);
  *(uint4*)(Fo + 8) = make_uint4(pkw[4], pkw[5], pkw[6], pkw[7]);
}

// ---------------- Kernel 4: projection + pixel-shuffle + residual ----------------
// grid (16 nb, 64 mb, 2 side). Coalesced IO via LDS-staged epilogue.
__global__ __launch_bounds__(256) void k_proj(
    const unsigned short* __restrict__ Fbf,
    const unsigned short* __restrict__ W3bf,
    const float* __restrict__ bl3, const float* __restrict__ br3,
    const float* __restrict__ beta, const float* __restrict__ gamma,
    const float* __restrict__ xl, const float* __restrict__ xr,
    float* __restrict__ out)
{
  const int nb = blockIdx.x, mb = blockIdx.y, side = blockIdx.z;
  const unsigned short* F  = Fbf + (size_t)side*524288 + (size_t)mb*8192;
  const unsigned short* W3 = W3bf + (size_t)side*262144 + (size_t)nb*16384;
  const float* b3  = (side ? br3 : bl3) + nb*128;
  const float* scl = side ? gamma : beta;
  const float* xin = (side ? xr : xl) + (size_t)mb*131072;
  float* op = out + (size_t)side*8388608 + (size_t)mb*131072;

  const int t = threadIdx.x;
  const int w = t >> 6, l = t & 63, lo = l & 15, g = l >> 4;

  // [0,16K) Ft ; [16K,48K) B3 ; epilogue: S f32 [8][1032] overlays from 0
  __shared__ __align__(16) unsigned char lds[49152];
  unsigned char* Ft = lds;
  unsigned char* B3 = lds + 16384;
  float* Sf = (float*)lds;

  {
    const uint4* src = (const uint4*)F;
#pragma unroll
    for (int j = 0; j < 4; ++j) {
      const int idx = t + 256*j;
      const int dst = idx*16;
      const int row = dst >> 8;
      *(uint4*)(Ft + dst) = src[(dst ^ ((row & 7) << 4)) >> 4];
    }
  }
  {
    const int nl = t >> 1, half = t & 1;
    const unsigned short* wsrc = W3 + (size_t)nl*128 + half*64;
#pragma unroll
    for (int ch = 0; ch < 8; ++ch) {
      const uint4 v = *(const uint4*)(wsrc + ch*8);
      const int inrow = (half*128 + ch*16) ^ ((nl & 7) << 4);
      *(uint4*)(B3 + nl*256 + inrow) = v;
    }
  }
  __syncthreads();

  f32x4 acc[4][2];
#pragma unroll
  for (int a=0;a<4;a++) { acc[a][0] = (f32x4)0.0f; acc[a][1] = (f32x4)0.0f; }

  bf16x8 af[4][4];
#pragma unroll
  for (int mf = 0; mf < 4; ++mf) {
    const int row = mf*16 + lo;
#pragma unroll
    for (int kc = 0; kc < 4; ++kc)
      af[mf][kc] = *(const bf16x8*)(Ft + row*256 + ((kc*64 + g*16) ^ ((row & 7) << 4)));
  }
#pragma unroll
  for (int kc = 0; kc < 4; ++kc)
#pragma unroll
    for (int nf = 0; nf < 2; ++nf) {
      const int n = w*32 + nf*16 + lo;
      const bf16x8 bb = *(const bf16x8*)(B3 + n*256 + ((kc*64 + g*16) ^ ((n & 7) << 4)));
#pragma unroll
      for (int mf = 0; mf < 4; ++mf)
        acc[mf][nf] = mfma16(af[mf][kc], bb, acc[mf][nf]);
    }

  __syncthreads();   // Ft/B3 fully consumed; reuse as Sf

  // stage scaled outputs into S[cl=0..7][pix=0..1023] (stride 1032 f32)
  {
    const int r4 = (lo >> 2) & 3, sc = lo & 3;
#pragma unroll
    for (int nf = 0; nf < 2; ++nf) {
      const int cl = w*2 + nf;
      const int n16 = w*32 + nf*16 + lo;
      const float scc = scl[nb*8 + cl];
      const float bb3 = b3[n16];
#pragma unroll
      for (int mf = 0; mf < 4; ++mf)
#pragma unroll
        for (int rr = 0; rr < 4; ++rr) {
          const int pi = mf*16 + g*4 + rr;
          const int h = pi >> 3, wc = pi & 7;
          Sf[cl*1032 + h*128 + r4*32 + wc*4 + sc] = scc*(acc[mf][nf][rr] + bb3);
        }
    }
  }
  __syncthreads();

  // coalesced residual + store: 8 rows of 1024 f32, 4KB contiguous per instr
#pragma unroll
  for (int j = 0; j < 8; ++j) {
    const int pix = t*4;
    const float4 s = *(const float4*)(Sf + j*1032 + pix);
    const size_t gaddr = (size_t)(nb*8 + j)*1024 + pix;
    const float4 xv = *(const float4*)(xin + gaddr);
    float4 r;
    r.x = xv.x + s.x; r.y = xv.y + s.y; r.z = xv.z + s.z; r.w = xv.w + s.w;
    *(float4*)(op + gaddr) = r;
  }
}

extern "C" void kernel_launch(void* const* d_in, const int* in_sizes, int n_in,
                              void* d_out, int out_size, void* d_ws, size_t ws_size,
                              hipStream_t stream) {
  (void)in_sizes; (void)n_in; (void)out_size; (void)ws_size;
  const float* xl   = (const float*)d_in[0];
  const float* xr   = (const float*)d_in[1];
  const float* lnwl = (const float*)d_in[2];
  const float* lnbl = (const float*)d_in[3];
  const float* lnwr = (const float*)d_in[4];
  const float* lnbr = (const float*)d_in[5];
  const float* Wl1  = (const float*)d_in[6];
  const float* bl1  = (const float*)d_in[7];
  const float* Wr1  = (const float*)d_in[8];
  const float* br1  = (const float*)d_in[9];
  const float* Wl2  = (const float*)d_in[10];
  const float* bl2  = (const float*)d_in[11];
  const float* Wr2  = (const float*)d_in[12];
  const float* br2  = (const float*)d_in[13];
  const float* pos  = (const float*)d_in[14];
  const float* beta = (const float*)d_in[15];
  const float* gamma= (const float*)d_in[16];
  const float* Wl3  = (const float*)d_in[17];
  const float* bl3  = (const float*)d_in[18];
  const float* Wr3  = (const float*)d_in[19];
  const float* br3  = (const float*)d_in[20];

  float* muW = (float*)d_ws;                            // [2][64][1024]
  float* rsW = muW + 131072;                            // [2][64][1024]
  float* bqW = rsW + 131072;                            // [2][128]
  unsigned short* Wq   = (unsigned short*)(bqW + 256);  // [2][32][128][64]
  unsigned short* Wv   = Wq + 524288;                   // [2][32][128][64]
  unsigned short* Qbf  = Wv + 524288;                   // [2][4096][128]
  unsigned short* Vtbf = Qbf + 1048576;                 // [2][128][4096]
  unsigned short* Fbf  = Vtbf + 1048576;                // [2][4096][128]
  unsigned short* W3bf = Fbf + 1048576;                 // [2][2048][128]
  unsigned short* Cpart = W3bf + 524288;                // [1024][128][64] bf16 (16.8MB)
  float* Opart = (float*)Cpart;                         // alias: [2][64][4][64][128] f32
  float* Lpart = (float*)(Cpart + 8388608);             // [2][64][4][64] f32

  k_lnstats<<<256, 256, 0, stream>>>(xl, xr, muW, rsW);
  k_wprep<<<256, 256, 0, stream>>>(lnwl, lnbl, lnwr, lnbr,
      Wl1, bl1, Wr1, br1, Wl2, Wr2, Wq, Wv, bqW);
  k_w3prep<<<512, 256, 0, stream>>>(Wl3, Wr3, W3bf);
  k_conv<<<1024, 256, 0, stream>>>(xl, xr, Wq, Wv, muW, rsW, Cpart);
  k_convred<<<256, 256, 0, stream>>>(Cpart, bqW, bl2, br2, pos, Qbf, Vtbf);
  k_attn<<<dim3(64, 4, 2), 256, 0, stream>>>(Qbf, Vtbf, Opart, Lpart);
  k_reduce<<<256, 256, 0, stream>>>(Opart, Lpart, Fbf);
  k_proj<<<dim3(16, 64, 2), 256, 0, stream>>>(Fbf, W3bf, bl3, br3,
      beta, gamma, xl, xr, (float*)d_out);
}